// Round 1
// baseline (214.462 us; speedup 1.0000x reference)
//
#include <hip/hip_runtime.h>
#include <math.h>

#define H0 3072
#define HC 2048
#define OFF 512
#define NA 21
#define NAB 441
#define KWIN 2028

// ws layout (bytes); total ~4.4 MB
#define WS_SCAL 128                       // floats: [0]mean_t [1]mean_f [2]t_var [3]sh_x [4]sh_y
#define WS_P1   256                       // 512*3 doubles
#define WS_R    16384                     // Rv: 2048*21 doubles
#define WS_R2   (16384 + 2048*21*8)       // Rv2: 2048*21 doubles
#define WS_DEN  720896                    // 441 floats
#define WS_CCV  724992                    // 441 doubles
#define WS_CP   786432                    // 2048*441 floats

// ---------------- K1: sums over 2048^2 crops ----------------
__global__ void k_sums(const float* __restrict__ fr, const float* __restrict__ tp,
                       double* __restrict__ p1) {
    __shared__ double rs[256 * 3];
    double st = 0, st2 = 0, sf = 0;
    const int n = HC * HC;
    for (int i = blockIdx.x * blockDim.x + threadIdx.x; i < n; i += gridDim.x * blockDim.x) {
        int x = i >> 11, y = i & 2047;
        size_t addr = (size_t)(OFF + x) * H0 + OFF + y;
        double t = tp[addr], f = fr[addr];
        st += t; st2 += t * t; sf += f;
    }
    int tid = threadIdx.x;
    rs[tid] = st; rs[256 + tid] = st2; rs[512 + tid] = sf;
    __syncthreads();
    for (int off = 128; off > 0; off >>= 1) {
        if (tid < off) {
            rs[tid] += rs[tid + off];
            rs[256 + tid] += rs[256 + tid + off];
            rs[512 + tid] += rs[512 + tid + off];
        }
        __syncthreads();
    }
    if (tid == 0) {
        p1[blockIdx.x * 3 + 0] = rs[0];
        p1[blockIdx.x * 3 + 1] = rs[256];
        p1[blockIdx.x * 3 + 2] = rs[512];
    }
}

__global__ void k_sums_final(const double* __restrict__ p1, float* __restrict__ scal) {
    __shared__ double rs[512 * 3];
    int tid = threadIdx.x;
    rs[tid] = p1[tid * 3 + 0];
    rs[512 + tid] = p1[tid * 3 + 1];
    rs[1024 + tid] = p1[tid * 3 + 2];
    __syncthreads();
    for (int off = 256; off > 0; off >>= 1) {
        if (tid < off) {
            rs[tid] += rs[tid + off];
            rs[512 + tid] += rs[512 + tid + off];
            rs[1024 + tid] += rs[1024 + tid + off];
        }
        __syncthreads();
    }
    if (tid == 0) {
        double N = (double)HC * (double)HC;
        double st = rs[0], st2 = rs[512], sf = rs[1024];
        float mt = (float)(st / N);
        float mf = (float)(sf / N);
        double m = (double)mt;
        double tv = st2 - 2.0 * m * st + N * m * m;   // sum((t - mt)^2) with f32 mean
        scal[0] = mt;
        scal[1] = mf;
        scal[2] = (float)tv + 1e-8f;                  // t_var
    }
}

// ---------------- K2: per-row 2028-wide window sums (21 windows) ----------------
__global__ void k_rowpool(const float* __restrict__ fr,
                          double* __restrict__ Rv, double* __restrict__ Rv2) {
    __shared__ float row[2048];
    __shared__ double s1[256], s2[256];
    int x = blockIdx.x, tid = threadIdx.x;
    const float* src = fr + (size_t)(OFF + x) * H0 + OFF;
    double a = 0, b = 0;
    for (int k = 0; k < 8; k++) {
        int y = tid + k * 256;
        float v = src[y];
        row[y] = v;
        a += v; b += (double)v * v;
    }
    s1[tid] = a; s2[tid] = b;
    __syncthreads();
    for (int off = 128; off > 0; off >>= 1) {
        if (tid < off) { s1[tid] += s1[tid + off]; s2[tid] += s2[tid + off]; }
        __syncthreads();
    }
    if (tid < NA) {
        double h1 = 0, h2 = 0;
        for (int y = 0; y < tid; y++)        { float v = row[y]; h1 += v; h2 += (double)v * v; }
        for (int y = tid + KWIN; y < 2048; y++){ float v = row[y]; h1 += v; h2 += (double)v * v; }
        Rv [x * NA + tid] = s1[0] - h1;
        Rv2[x * NA + tid] = s2[0] - h2;
    }
}

// ---------------- K3: finish pool over rows -> denom[441] ----------------
__global__ void k_pool_final(const double* __restrict__ Rv, const double* __restrict__ Rv2,
                             const float* __restrict__ scal, float* __restrict__ den) {
    __shared__ double red[512];
    __shared__ double TT[2 * NA];
    int tid = threadIdx.x;
    for (int c = 0; c < 2; c++) {
        const double* R = c ? Rv2 : Rv;
        for (int j = 0; j < NA; j++) {
            double s = 0;
            for (int x = tid; x < 2048; x += 512) s += R[x * NA + j];
            red[tid] = s;
            __syncthreads();
            for (int off = 256; off > 0; off >>= 1) {
                if (tid < off) red[tid] += red[tid + off];
                __syncthreads();
            }
            if (tid == 0) TT[c * NA + j] = red[0];
            __syncthreads();
        }
    }
    float tvar = scal[2];
    if (tid < NAB) {
        int i = tid / NA, j = tid - (tid / NA) * NA;
        double h0 = 0, h1 = 0;
        for (int x = 0; x < i; x++)           { h0 += Rv[x * NA + j]; h1 += Rv2[x * NA + j]; }
        for (int x = i + KWIN; x < 2048; x++) { h0 += Rv[x * NA + j]; h1 += Rv2[x * NA + j]; }
        double area = (double)KWIN * (double)KWIN;
        float lm0 = (float)((TT[j] - h0) / area);
        float lm1 = (float)((TT[NA + j] - h1) / area);
        float iv = lm1 - (lm0 * lm0) / 4194304.0f + 1e-8f;
        if (iv < 0.f) iv = 0.f;
        den[tid] = sqrtf(tvar * iv);
    }
}

// ---------------- K4: direct circular cross-correlation at 441 lags ----------------
#define RB 8
#define YC 256
#define TROWS 28
#define TCOLS 276
#define TSTR 284
#define ISTR 260

__global__ __launch_bounds__(192) void k_corr(const float* __restrict__ fr,
                                              const float* __restrict__ tp,
                                              const float* __restrict__ scal,
                                              float* __restrict__ cp) {
    __shared__ __align__(16) float smem[TROWS * TSTR + RB * ISTR];
    float* t_s = smem;
    float* i_s = smem + TROWS * TSTR;
    int tid = threadIdx.x;
    int bid = blockIdx.x;
    int xb = bid >> 3, yb = bid & 7;
    int x0 = xb * RB, y0 = yb * YC;
    float mt = scal[0], mf = scal[1];

    for (int idx = tid; idx < TROWS * TCOLS; idx += 192) {
        int i = idx / TCOLS, j = idx - i * TCOLS;
        int gr = (x0 - 10 + i + HC) & (HC - 1);
        int gc = (y0 - 10 + j + HC) & (HC - 1);
        t_s[i * TSTR + j] = tp[(size_t)(OFF + gr) * H0 + OFF + gc] - mt;
    }
    for (int idx = tid; idx < RB * YC; idx += 192) {
        int i = idx >> 8, j = idx & 255;
        i_s[i * ISTR + j] = fr[(size_t)(OFF + x0 + i) * H0 + OFF + y0 + j] - mf;
    }
    __syncthreads();

    float acc[NA];
    int xl = tid / NA, a = tid - xl * NA;
    bool active = tid < RB * NA;
    if (active) {
#pragma unroll
        for (int b = 0; b < NA; b++) acc[b] = 0.f;
        const float* tr = &t_s[(xl + 20 - a) * TSTR];
        const float* ir = &i_s[xl * ISTR];
        float4 w4[6];
#pragma unroll
        for (int i = 0; i < 6; i++) w4[i] = *reinterpret_cast<const float4*>(&tr[i * 4]);

        auto step = [&](int j, float iv) {
#pragma unroll
            for (int b = 0; b < NA; ++b) {
                int wi = j + 20 - b;
                float wv = (wi & 3) == 0 ? w4[wi >> 2].x
                         : (wi & 3) == 1 ? w4[wi >> 2].y
                         : (wi & 3) == 2 ? w4[wi >> 2].z
                                         : w4[wi >> 2].w;
                acc[b] = fmaf(iv, wv, acc[b]);
            }
        };

        for (int yy = 0; yy < YC; yy += 4) {
            float4 im = *reinterpret_cast<const float4*>(&ir[yy]);
            step(0, im.x); step(1, im.y); step(2, im.z); step(3, im.w);
            if (yy + 4 < YC) {
#pragma unroll
                for (int i = 0; i < 5; i++) w4[i] = w4[i + 1];
                w4[5] = *reinterpret_cast<const float4*>(&tr[yy + 24]);
            }
        }
    }
    __syncthreads();                 // everyone done with t_s; reuse as reduction buffer
    float* red = smem;               // red[(a*21+b)*8 + xl], 3528 floats
    if (active) {
#pragma unroll
        for (int b = 0; b < NA; b++) red[(a * NA + b) * RB + xl] = acc[b];
    }
    __syncthreads();
    for (int ab = tid; ab < NAB; ab += 192) {
        float s = 0.f;
#pragma unroll
        for (int k = 0; k < RB; k++) s += red[ab * RB + k];
        cp[(size_t)bid * NAB + ab] = s;
    }
}

// ---------------- K5a: deterministic reduction of per-block partials ----------------
__global__ void k_ccreduce(const float* __restrict__ cp, double* __restrict__ ccv) {
    __shared__ double red[256];
    int ab = blockIdx.x, tid = threadIdx.x;
    double s = 0;
    for (int blk = tid; blk < 2048; blk += 256) s += (double)cp[(size_t)blk * NAB + ab];
    red[tid] = s;
    __syncthreads();
    for (int off = 128; off > 0; off >>= 1) {
        if (tid < off) red[tid] += red[tid + off];
        __syncthreads();
    }
    if (tid == 0) ccv[ab] = red[0];
}

// ---------------- K5b: ncc, argmax (first-max), log-parabola ----------------
__global__ void k_peak(const double* __restrict__ ccv, const float* __restrict__ den,
                       float* __restrict__ scal, float* __restrict__ out) {
    __shared__ float ncc[NAB];
    __shared__ float bv[512];
    __shared__ int bi_[512];
    int tid = threadIdx.x;
    if (tid < NAB) {
        float c = fabsf((float)ccv[tid]);
        float v = c / den[tid];
        if (v != v) v = 0.f;
        ncc[tid] = v;
    }
    __syncthreads();
    bv[tid] = (tid < NAB) ? ncc[tid] : -1e38f;
    bi_[tid] = (tid < NAB) ? tid : 0;
    __syncthreads();
    for (int off = 256; off > 0; off >>= 1) {
        if (tid < off) {
            float v2 = bv[tid + off]; int i2 = bi_[tid + off];
            if (v2 > bv[tid] || (v2 == bv[tid] && i2 < bi_[tid])) { bv[tid] = v2; bi_[tid] = i2; }
        }
        __syncthreads();
    }
    if (tid == 0) {
        int am = bi_[0];
        int sx = am / NA, sy = am - (am / NA) * NA;
        auto L = [&](int i, int j) {
            int ii = ((i % NA) + NA) % NA;
            int jj = ((j % NA) + NA) % NA;
            return logf(ncc[ii * NA + jj]);
        };
        float l0 = L(sx, sy);
        float lxm = L(sx - 1, sy), lxp = L(sx + 1, sy);
        float lym = L(sx, sy - 1), lyp = L(sx, sy + 1);
        float four = 4.f * l0;
        float shx = -(float)(sx - 10) - (lxm - lxp) / (2.f * lxm - four + 2.f * lxp);
        float shy = -(float)(sy - 10) - (lym - lyp) / (2.f * lym - four + 2.f * lyp);
        scal[3] = shx; scal[4] = shy;
        out[(size_t)H0 * H0]     = shx;
        out[(size_t)H0 * H0 + 1] = shy;
    }
}

// ---------------- K6: bilinear translate + transposed flatten ----------------
__global__ __launch_bounds__(256) void k_translate(const float* __restrict__ fr,
                                                   const float* __restrict__ scal,
                                                   float* __restrict__ out) {
    __shared__ float T[65 * 67];
    int tid = threadIdx.x;
    int bx = blockIdx.x % 48, by = blockIdx.x / 48;
    int r0 = bx * 64, c0 = by * 64;
    float dx = scal[3], dy = scal[4];
    float fy = -dy, Fy = floorf(fy), wr = fy - Fy;
    float fx = -dx, Fx = floorf(fx), wc = fx - Fx;
    int R0 = r0 + (int)Fy, C0 = c0 + (int)Fx;
    for (int idx = tid; idx < 65 * 65; idx += 256) {
        int i = idx / 65, j = idx - i * 65;
        int gr = R0 + i, gc = C0 + j;
        float v = 0.f;
        if (gr >= 0 && gr < H0 && gc >= 0 && gc < H0) v = fr[(size_t)gr * H0 + gc];
        T[i * 67 + j] = v;
    }
    __syncthreads();
    float w00 = (1.f - wr) * (1.f - wc), w01 = (1.f - wr) * wc;
    float w10 = wr * (1.f - wc),        w11 = wr * wc;
    int rl = (tid & 15) * 4;
    int cl0 = tid >> 4;
    auto S = [&](int rr, int cl) {
        return w00 * T[rr * 67 + cl] + w01 * T[rr * 67 + cl + 1] +
               w10 * T[(rr + 1) * 67 + cl] + w11 * T[(rr + 1) * 67 + cl + 1];
    };
    for (int q = 0; q < 4; q++) {
        int cl = cl0 + q * 16;
        float4 res = make_float4(S(rl, cl), S(rl + 1, cl), S(rl + 2, cl), S(rl + 3, cl));
        *reinterpret_cast<float4*>(&out[(size_t)(c0 + cl) * H0 + r0 + rl]) = res;
    }
}

extern "C" void kernel_launch(void* const* d_in, const int* in_sizes, int n_in,
                              void* d_out, int out_size, void* d_ws, size_t ws_size,
                              hipStream_t stream) {
    const float* fr = (const float*)d_in[0];
    const float* tp = (const float*)d_in[1];
    float* out = (float*)d_out;
    char* ws = (char*)d_ws;
    float*  scal = (float*)(ws + WS_SCAL);
    double* p1   = (double*)(ws + WS_P1);
    double* Rv   = (double*)(ws + WS_R);
    double* Rv2  = (double*)(ws + WS_R2);
    float*  den  = (float*)(ws + WS_DEN);
    double* ccv  = (double*)(ws + WS_CCV);
    float*  cp   = (float*)(ws + WS_CP);

    k_sums      <<<512, 256, 0, stream>>>(fr, tp, p1);
    k_sums_final<<<1, 512, 0, stream>>>(p1, scal);
    k_rowpool   <<<2048, 256, 0, stream>>>(fr, Rv, Rv2);
    k_pool_final<<<1, 512, 0, stream>>>(Rv, Rv2, scal, den);
    k_corr      <<<2048, 192, 0, stream>>>(fr, tp, scal, cp);
    k_ccreduce  <<<NAB, 256, 0, stream>>>(cp, ccv);
    k_peak      <<<1, 512, 0, stream>>>(ccv, den, scal, out);
    k_translate <<<2304, 256, 0, stream>>>(fr, scal, out);
}

// Round 2
// 138.132 us; speedup vs baseline: 1.5526x; 1.5526x over previous
//
#include <hip/hip_runtime.h>
#include <math.h>

#define H0 3072
#define HC 2048
#define OFF 512
#define NA 21
#define NAB 441
#define KWIN 2028

// ws layout (bytes); total ~4.4 MB
#define WS_SCAL 128                       // floats: [0]mean_t [1]mean_f [2]t_var [3]sh_x [4]sh_y
#define WS_P1   256                       // 512*3 doubles
#define WS_TT   12800                     // 42 doubles (column totals)
#define WS_R    16384                     // Rv : [j][x] = j*2048+x, 2048*21 doubles
#define WS_R2   (16384 + 2048*21*8)       // Rv2: same layout
#define WS_DEN  720896                    // 441 floats
#define WS_CCV  724992                    // 441 doubles
#define WS_CP   786432                    // 2048*441 floats

// ---------------- K1: sums over 2048^2 crops ----------------
__global__ void k_sums(const float* __restrict__ fr, const float* __restrict__ tp,
                       double* __restrict__ p1) {
    __shared__ double rs[256 * 3];
    double st = 0, st2 = 0, sf = 0;
    const int n = HC * HC;
    for (int i = blockIdx.x * blockDim.x + threadIdx.x; i < n; i += gridDim.x * blockDim.x) {
        int x = i >> 11, y = i & 2047;
        size_t addr = (size_t)(OFF + x) * H0 + OFF + y;
        double t = tp[addr], f = fr[addr];
        st += t; st2 += t * t; sf += f;
    }
    int tid = threadIdx.x;
    rs[tid] = st; rs[256 + tid] = st2; rs[512 + tid] = sf;
    __syncthreads();
    for (int off = 128; off > 0; off >>= 1) {
        if (tid < off) {
            rs[tid] += rs[tid + off];
            rs[256 + tid] += rs[256 + tid + off];
            rs[512 + tid] += rs[512 + tid + off];
        }
        __syncthreads();
    }
    if (tid == 0) {
        p1[blockIdx.x * 3 + 0] = rs[0];
        p1[blockIdx.x * 3 + 1] = rs[256];
        p1[blockIdx.x * 3 + 2] = rs[512];
    }
}

__global__ void k_sums_final(const double* __restrict__ p1, float* __restrict__ scal) {
    __shared__ double rs[512 * 3];
    int tid = threadIdx.x;
    rs[tid] = p1[tid * 3 + 0];
    rs[512 + tid] = p1[tid * 3 + 1];
    rs[1024 + tid] = p1[tid * 3 + 2];
    __syncthreads();
    for (int off = 256; off > 0; off >>= 1) {
        if (tid < off) {
            rs[tid] += rs[tid + off];
            rs[512 + tid] += rs[512 + tid + off];
            rs[1024 + tid] += rs[1024 + tid + off];
        }
        __syncthreads();
    }
    if (tid == 0) {
        double N = (double)HC * (double)HC;
        double st = rs[0], st2 = rs[512], sf = rs[1024];
        float mt = (float)(st / N);
        float mf = (float)(sf / N);
        double m = (double)mt;
        double tv = st2 - 2.0 * m * st + N * m * m;   // sum((t - mt)^2) with f32 mean
        scal[0] = mt;
        scal[1] = mf;
        scal[2] = (float)tv + 1e-8f;                  // t_var
    }
}

// ---------------- K2: per-row 2028-wide window sums (21 windows), transposed out ----------------
__global__ void k_rowpool(const float* __restrict__ fr,
                          double* __restrict__ Rv, double* __restrict__ Rv2) {
    __shared__ float row[2048];
    __shared__ double s1[256], s2[256];
    int x = blockIdx.x, tid = threadIdx.x;
    const float* src = fr + (size_t)(OFF + x) * H0 + OFF;
    double a = 0, b = 0;
    for (int k = 0; k < 8; k++) {
        int y = tid + k * 256;
        float v = src[y];
        row[y] = v;
        a += v; b += (double)v * v;
    }
    s1[tid] = a; s2[tid] = b;
    __syncthreads();
    for (int off = 128; off > 0; off >>= 1) {
        if (tid < off) { s1[tid] += s1[tid + off]; s2[tid] += s2[tid + off]; }
        __syncthreads();
    }
    if (tid < NA) {
        double h1 = 0, h2 = 0;
        for (int y = 0; y < tid; y++)         { float v = row[y]; h1 += v; h2 += (double)v * v; }
        for (int y = tid + KWIN; y < 2048; y++){ float v = row[y]; h1 += v; h2 += (double)v * v; }
        Rv [(size_t)tid * 2048 + x] = s1[0] - h1;
        Rv2[(size_t)tid * 2048 + x] = s2[0] - h2;
    }
}

// ---------------- K3a: column totals TT[42] (parallel over 42 blocks) ----------------
__global__ void k_colsum(const double* __restrict__ Rv, const double* __restrict__ Rv2,
                         double* __restrict__ TT) {
    __shared__ double red[256];
    int b = blockIdx.x, tid = threadIdx.x;
    const double* R = (b >= NA) ? (Rv2 + (size_t)(b - NA) * 2048)
                                : (Rv  + (size_t)b * 2048);
    double s = 0;
    for (int x = tid; x < 2048; x += 256) s += R[x];
    red[tid] = s;
    __syncthreads();
    for (int off = 128; off > 0; off >>= 1) {
        if (tid < off) red[tid] += red[tid + off];
        __syncthreads();
    }
    if (tid == 0) TT[b] = red[0];
}

// ---------------- K3b: denom[441] from totals minus head/tail (<=80 loads/thread) -----
__global__ void k_den(const double* __restrict__ Rv, const double* __restrict__ Rv2,
                      const double* __restrict__ TT, const float* __restrict__ scal,
                      float* __restrict__ den) {
    int tid = threadIdx.x;
    if (tid >= NAB) return;
    int i = tid / NA, j = tid - (tid / NA) * NA;
    const double* R0 = Rv  + (size_t)j * 2048;
    const double* R1 = Rv2 + (size_t)j * 2048;
    double h0 = 0, h1 = 0;
    for (int x = 0; x < i; x++)           { h0 += R0[x]; h1 += R1[x]; }
    for (int x = i + KWIN; x < 2048; x++) { h0 += R0[x]; h1 += R1[x]; }
    double area = (double)KWIN * (double)KWIN;
    float lm0 = (float)((TT[j] - h0) / area);
    float lm1 = (float)((TT[NA + j] - h1) / area);
    float iv = lm1 - (lm0 * lm0) / 4194304.0f + 1e-8f;
    if (iv < 0.f) iv = 0.f;
    den[tid] = sqrtf(scal[2] * iv);
}

// ---------------- K4: direct circular cross-correlation at 441 lags ----------------
#define RB 8
#define YC 256
#define TROWS 28
#define TCOLS 276
#define TSTR 284
#define ISTR 260

__global__ __launch_bounds__(192) void k_corr(const float* __restrict__ fr,
                                              const float* __restrict__ tp,
                                              const float* __restrict__ scal,
                                              float* __restrict__ cp) {
    __shared__ __align__(16) float smem[TROWS * TSTR + RB * ISTR];
    float* t_s = smem;
    float* i_s = smem + TROWS * TSTR;
    int tid = threadIdx.x;
    int bid = blockIdx.x;
    int xb = bid >> 3, yb = bid & 7;
    int x0 = xb * RB, y0 = yb * YC;
    float mt = scal[0], mf = scal[1];

    for (int idx = tid; idx < TROWS * TCOLS; idx += 192) {
        int i = idx / TCOLS, j = idx - i * TCOLS;
        int gr = (x0 - 10 + i + HC) & (HC - 1);
        int gc = (y0 - 10 + j + HC) & (HC - 1);
        t_s[i * TSTR + j] = tp[(size_t)(OFF + gr) * H0 + OFF + gc] - mt;
    }
    for (int idx = tid; idx < RB * YC; idx += 192) {
        int i = idx >> 8, j = idx & 255;
        i_s[i * ISTR + j] = fr[(size_t)(OFF + x0 + i) * H0 + OFF + y0 + j] - mf;
    }
    __syncthreads();

    float acc[NA];
    int xl = tid / NA, a = tid - xl * NA;
    bool active = tid < RB * NA;
    if (active) {
#pragma unroll
        for (int b = 0; b < NA; b++) acc[b] = 0.f;
        const float* tr = &t_s[(xl + 20 - a) * TSTR];
        const float* ir = &i_s[xl * ISTR];
        float4 w4[6];
#pragma unroll
        for (int i = 0; i < 6; i++) w4[i] = *reinterpret_cast<const float4*>(&tr[i * 4]);

        auto step = [&](int j, float iv) {
#pragma unroll
            for (int b = 0; b < NA; ++b) {
                int wi = j + 20 - b;
                float wv = (wi & 3) == 0 ? w4[wi >> 2].x
                         : (wi & 3) == 1 ? w4[wi >> 2].y
                         : (wi & 3) == 2 ? w4[wi >> 2].z
                                         : w4[wi >> 2].w;
                acc[b] = fmaf(iv, wv, acc[b]);
            }
        };

        for (int yy = 0; yy < YC; yy += 4) {
            float4 im = *reinterpret_cast<const float4*>(&ir[yy]);
            step(0, im.x); step(1, im.y); step(2, im.z); step(3, im.w);
            if (yy + 4 < YC) {
#pragma unroll
                for (int i = 0; i < 5; i++) w4[i] = w4[i + 1];
                w4[5] = *reinterpret_cast<const float4*>(&tr[yy + 24]);
            }
        }
    }
    __syncthreads();                 // everyone done with t_s; reuse as reduction buffer
    float* red = smem;               // red[(a*21+b)*8 + xl], 3528 floats
    if (active) {
#pragma unroll
        for (int b = 0; b < NA; b++) red[(a * NA + b) * RB + xl] = acc[b];
    }
    __syncthreads();
    for (int ab = tid; ab < NAB; ab += 192) {
        float s = 0.f;
#pragma unroll
        for (int k = 0; k < RB; k++) s += red[ab * RB + k];
        cp[(size_t)bid * NAB + ab] = s;
    }
}

// ---------------- K5a: deterministic reduction of per-block partials ----------------
__global__ void k_ccreduce(const float* __restrict__ cp, double* __restrict__ ccv) {
    __shared__ double red[256];
    int ab = blockIdx.x, tid = threadIdx.x;
    double s = 0;
    for (int blk = tid; blk < 2048; blk += 256) s += (double)cp[(size_t)blk * NAB + ab];
    red[tid] = s;
    __syncthreads();
    for (int off = 128; off > 0; off >>= 1) {
        if (tid < off) red[tid] += red[tid + off];
        __syncthreads();
    }
    if (tid == 0) ccv[ab] = red[0];
}

// ---------------- K5b: ncc, argmax (first-max), log-parabola ----------------
__global__ void k_peak(const double* __restrict__ ccv, const float* __restrict__ den,
                       float* __restrict__ scal, float* __restrict__ out) {
    __shared__ float ncc[NAB];
    __shared__ float bv[512];
    __shared__ int bi_[512];
    int tid = threadIdx.x;
    if (tid < NAB) {
        float c = fabsf((float)ccv[tid]);
        float v = c / den[tid];
        if (v != v) v = 0.f;
        ncc[tid] = v;
    }
    __syncthreads();
    bv[tid] = (tid < NAB) ? ncc[tid] : -1e38f;
    bi_[tid] = (tid < NAB) ? tid : 0;
    __syncthreads();
    for (int off = 256; off > 0; off >>= 1) {
        if (tid < off) {
            float v2 = bv[tid + off]; int i2 = bi_[tid + off];
            if (v2 > bv[tid] || (v2 == bv[tid] && i2 < bi_[tid])) { bv[tid] = v2; bi_[tid] = i2; }
        }
        __syncthreads();
    }
    if (tid == 0) {
        int am = bi_[0];
        int sx = am / NA, sy = am - (am / NA) * NA;
        auto L = [&](int i, int j) {
            int ii = ((i % NA) + NA) % NA;
            int jj = ((j % NA) + NA) % NA;
            return logf(ncc[ii * NA + jj]);
        };
        float l0 = L(sx, sy);
        float lxm = L(sx - 1, sy), lxp = L(sx + 1, sy);
        float lym = L(sx, sy - 1), lyp = L(sx, sy + 1);
        float four = 4.f * l0;
        float shx = -(float)(sx - 10) - (lxm - lxp) / (2.f * lxm - four + 2.f * lxp);
        float shy = -(float)(sy - 10) - (lym - lyp) / (2.f * lym - four + 2.f * lyp);
        scal[3] = shx; scal[4] = shy;
        out[(size_t)H0 * H0]     = shx;
        out[(size_t)H0 * H0 + 1] = shy;
    }
}

// ---------------- K6: bilinear translate + transposed flatten ----------------
__global__ __launch_bounds__(256) void k_translate(const float* __restrict__ fr,
                                                   const float* __restrict__ scal,
                                                   float* __restrict__ out) {
    __shared__ float T[65 * 67];
    int tid = threadIdx.x;
    int bx = blockIdx.x % 48, by = blockIdx.x / 48;
    int r0 = bx * 64, c0 = by * 64;
    float dx = scal[3], dy = scal[4];
    float fy = -dy, Fy = floorf(fy), wr = fy - Fy;
    float fx = -dx, Fx = floorf(fx), wc = fx - Fx;
    int R0 = r0 + (int)Fy, C0 = c0 + (int)Fx;
    for (int idx = tid; idx < 65 * 65; idx += 256) {
        int i = idx / 65, j = idx - i * 65;
        int gr = R0 + i, gc = C0 + j;
        float v = 0.f;
        if (gr >= 0 && gr < H0 && gc >= 0 && gc < H0) v = fr[(size_t)gr * H0 + gc];
        T[i * 67 + j] = v;
    }
    __syncthreads();
    float w00 = (1.f - wr) * (1.f - wc), w01 = (1.f - wr) * wc;
    float w10 = wr * (1.f - wc),        w11 = wr * wc;
    int rl = (tid & 15) * 4;
    int cl0 = tid >> 4;
    auto S = [&](int rr, int cl) {
        return w00 * T[rr * 67 + cl] + w01 * T[rr * 67 + cl + 1] +
               w10 * T[(rr + 1) * 67 + cl] + w11 * T[(rr + 1) * 67 + cl + 1];
    };
    for (int q = 0; q < 4; q++) {
        int cl = cl0 + q * 16;
        float4 res = make_float4(S(rl, cl), S(rl + 1, cl), S(rl + 2, cl), S(rl + 3, cl));
        *reinterpret_cast<float4*>(&out[(size_t)(c0 + cl) * H0 + r0 + rl]) = res;
    }
}

extern "C" void kernel_launch(void* const* d_in, const int* in_sizes, int n_in,
                              void* d_out, int out_size, void* d_ws, size_t ws_size,
                              hipStream_t stream) {
    const float* fr = (const float*)d_in[0];
    const float* tp = (const float*)d_in[1];
    float* out = (float*)d_out;
    char* ws = (char*)d_ws;
    float*  scal = (float*)(ws + WS_SCAL);
    double* p1   = (double*)(ws + WS_P1);
    double* TT   = (double*)(ws + WS_TT);
    double* Rv   = (double*)(ws + WS_R);
    double* Rv2  = (double*)(ws + WS_R2);
    float*  den  = (float*)(ws + WS_DEN);
    double* ccv  = (double*)(ws + WS_CCV);
    float*  cp   = (float*)(ws + WS_CP);

    k_sums      <<<512, 256, 0, stream>>>(fr, tp, p1);
    k_sums_final<<<1, 512, 0, stream>>>(p1, scal);
    k_rowpool   <<<2048, 256, 0, stream>>>(fr, Rv, Rv2);
    k_colsum    <<<2 * NA, 256, 0, stream>>>(Rv, Rv2, TT);
    k_den       <<<1, 512, 0, stream>>>(Rv, Rv2, TT, scal, den);
    k_corr      <<<2048, 192, 0, stream>>>(fr, tp, scal, cp);
    k_ccreduce  <<<NAB, 256, 0, stream>>>(cp, ccv);
    k_peak      <<<1, 512, 0, stream>>>(ccv, den, scal, out);
    k_translate <<<2304, 256, 0, stream>>>(fr, scal, out);
}

// Round 3
// 122.690 us; speedup vs baseline: 1.7480x; 1.1259x over previous
//
#include <hip/hip_runtime.h>
#include <math.h>

#define H0 3072
#define HC 2048
#define OFF 512
#define NA 21
#define NAB 441
#define KWIN 2028

// k_corr tiling
#define RB 12
#define YC 256
#define NXB 171                 // ceil(2048/12)
#define NBLK (NXB * 8)          // 1368
#define TROWS (RB + 20)         // 32
#define TCOLS 276
#define TSTR 276                // /4 = 69 (odd) -> quad-injective rows
#define ISTR 260

// ws layout (bytes)
#define WS_SCAL 128                       // floats: [0]mean_t [1]mean_f [2]t_var [3]sh_x [4]sh_y
#define WS_P1   256                       // 512*3 doubles
#define WS_TT   12800                     // 42 doubles (column totals)
#define WS_R    16384                     // Rv : [j][x] = j*2048+x, 2048*21 doubles
#define WS_R2   (16384 + 2048*21*8)       // Rv2: same layout
#define WS_DEN  720896                    // 441 floats
#define WS_CCV  724992                    // 441 doubles
#define WS_CP   786432                    // NBLK*441 floats

// ---------------- K1: sums over 2048^2 crops ----------------
__global__ void k_sums(const float* __restrict__ fr, const float* __restrict__ tp,
                       double* __restrict__ p1) {
    __shared__ double rs[256 * 3];
    double st = 0, st2 = 0, sf = 0;
    const int n = HC * HC;
    for (int i = blockIdx.x * blockDim.x + threadIdx.x; i < n; i += gridDim.x * blockDim.x) {
        int x = i >> 11, y = i & 2047;
        size_t addr = (size_t)(OFF + x) * H0 + OFF + y;
        double t = tp[addr], f = fr[addr];
        st += t; st2 += t * t; sf += f;
    }
    int tid = threadIdx.x;
    rs[tid] = st; rs[256 + tid] = st2; rs[512 + tid] = sf;
    __syncthreads();
    for (int off = 128; off > 0; off >>= 1) {
        if (tid < off) {
            rs[tid] += rs[tid + off];
            rs[256 + tid] += rs[256 + tid + off];
            rs[512 + tid] += rs[512 + tid + off];
        }
        __syncthreads();
    }
    if (tid == 0) {
        p1[blockIdx.x * 3 + 0] = rs[0];
        p1[blockIdx.x * 3 + 1] = rs[256];
        p1[blockIdx.x * 3 + 2] = rs[512];
    }
}

__global__ void k_sums_final(const double* __restrict__ p1, float* __restrict__ scal) {
    __shared__ double rs[512 * 3];
    int tid = threadIdx.x;
    rs[tid] = p1[tid * 3 + 0];
    rs[512 + tid] = p1[tid * 3 + 1];
    rs[1024 + tid] = p1[tid * 3 + 2];
    __syncthreads();
    for (int off = 256; off > 0; off >>= 1) {
        if (tid < off) {
            rs[tid] += rs[tid + off];
            rs[512 + tid] += rs[512 + tid + off];
            rs[1024 + tid] += rs[1024 + tid + off];
        }
        __syncthreads();
    }
    if (tid == 0) {
        double N = (double)HC * (double)HC;
        double st = rs[0], st2 = rs[512], sf = rs[1024];
        float mt = (float)(st / N);
        float mf = (float)(sf / N);
        double m = (double)mt;
        double tv = st2 - 2.0 * m * st + N * m * m;
        scal[0] = mt;
        scal[1] = mf;
        scal[2] = (float)tv + 1e-8f;
    }
}

// ---------------- K2: per-row 2028-wide window sums (21 windows), transposed out ----------------
__global__ void k_rowpool(const float* __restrict__ fr,
                          double* __restrict__ Rv, double* __restrict__ Rv2) {
    __shared__ float row[2048];
    __shared__ double s1[256], s2[256];
    int x = blockIdx.x, tid = threadIdx.x;
    const float* src = fr + (size_t)(OFF + x) * H0 + OFF;
    double a = 0, b = 0;
    for (int k = 0; k < 8; k++) {
        int y = tid + k * 256;
        float v = src[y];
        row[y] = v;
        a += v; b += (double)v * v;
    }
    s1[tid] = a; s2[tid] = b;
    __syncthreads();
    for (int off = 128; off > 0; off >>= 1) {
        if (tid < off) { s1[tid] += s1[tid + off]; s2[tid] += s2[tid + off]; }
        __syncthreads();
    }
    if (tid < NA) {
        double h1 = 0, h2 = 0;
        for (int y = 0; y < tid; y++)          { float v = row[y]; h1 += v; h2 += (double)v * v; }
        for (int y = tid + KWIN; y < 2048; y++){ float v = row[y]; h1 += v; h2 += (double)v * v; }
        Rv [(size_t)tid * 2048 + x] = s1[0] - h1;
        Rv2[(size_t)tid * 2048 + x] = s2[0] - h2;
    }
}

// ---------------- K3a: column totals TT[42] ----------------
__global__ void k_colsum(const double* __restrict__ Rv, const double* __restrict__ Rv2,
                         double* __restrict__ TT) {
    __shared__ double red[256];
    int b = blockIdx.x, tid = threadIdx.x;
    const double* R = (b >= NA) ? (Rv2 + (size_t)(b - NA) * 2048)
                                : (Rv  + (size_t)b * 2048);
    double s = 0;
    for (int x = tid; x < 2048; x += 256) s += R[x];
    red[tid] = s;
    __syncthreads();
    for (int off = 128; off > 0; off >>= 1) {
        if (tid < off) red[tid] += red[tid + off];
        __syncthreads();
    }
    if (tid == 0) TT[b] = red[0];
}

// ---------------- K3b: denom[441] ----------------
__global__ void k_den(const double* __restrict__ Rv, const double* __restrict__ Rv2,
                      const double* __restrict__ TT, const float* __restrict__ scal,
                      float* __restrict__ den) {
    int tid = threadIdx.x;
    if (tid >= NAB) return;
    int i = tid / NA, j = tid - (tid / NA) * NA;
    const double* R0 = Rv  + (size_t)j * 2048;
    const double* R1 = Rv2 + (size_t)j * 2048;
    double h0 = 0, h1 = 0;
    for (int x = 0; x < i; x++)           { h0 += R0[x]; h1 += R1[x]; }
    for (int x = i + KWIN; x < 2048; x++) { h0 += R0[x]; h1 += R1[x]; }
    double area = (double)KWIN * (double)KWIN;
    float lm0 = (float)((TT[j] - h0) / area);
    float lm1 = (float)((TT[NA + j] - h1) / area);
    float iv = lm1 - (lm0 * lm0) / 4194304.0f + 1e-8f;
    if (iv < 0.f) iv = 0.f;
    den[tid] = sqrtf(scal[2] * iv);
}

// ---------------- K4: direct circular cross-correlation at 441 lags ----------------
// thread (xl, a): acc[b] += I[x0+xl, y0+j] * t_s[(xl+20-a)][j+20-b], 24-px rotation-free window
#define COMP(v,c) ((c)==0?(v).x:((c)==1?(v).y:((c)==2?(v).z:(v).w)))
#define WS6(f) ((f)%6==0?w0:((f)%6==1?w1:((f)%6==2?w2:((f)%6==3?w3:((f)%6==4?w4:w5)))))
#define EIDX(p,q,b) (4*(p)+(q)+20-(b))
#define WC(e) COMP(WS6((e)>>2), (e)&3)
#define FMA21(p,q) do { float iv = COMP(im,(q)); \
    acc[0]  = fmaf(iv, WC(EIDX(p,q,0)),  acc[0]);  \
    acc[1]  = fmaf(iv, WC(EIDX(p,q,1)),  acc[1]);  \
    acc[2]  = fmaf(iv, WC(EIDX(p,q,2)),  acc[2]);  \
    acc[3]  = fmaf(iv, WC(EIDX(p,q,3)),  acc[3]);  \
    acc[4]  = fmaf(iv, WC(EIDX(p,q,4)),  acc[4]);  \
    acc[5]  = fmaf(iv, WC(EIDX(p,q,5)),  acc[5]);  \
    acc[6]  = fmaf(iv, WC(EIDX(p,q,6)),  acc[6]);  \
    acc[7]  = fmaf(iv, WC(EIDX(p,q,7)),  acc[7]);  \
    acc[8]  = fmaf(iv, WC(EIDX(p,q,8)),  acc[8]);  \
    acc[9]  = fmaf(iv, WC(EIDX(p,q,9)),  acc[9]);  \
    acc[10] = fmaf(iv, WC(EIDX(p,q,10)), acc[10]); \
    acc[11] = fmaf(iv, WC(EIDX(p,q,11)), acc[11]); \
    acc[12] = fmaf(iv, WC(EIDX(p,q,12)), acc[12]); \
    acc[13] = fmaf(iv, WC(EIDX(p,q,13)), acc[13]); \
    acc[14] = fmaf(iv, WC(EIDX(p,q,14)), acc[14]); \
    acc[15] = fmaf(iv, WC(EIDX(p,q,15)), acc[15]); \
    acc[16] = fmaf(iv, WC(EIDX(p,q,16)), acc[16]); \
    acc[17] = fmaf(iv, WC(EIDX(p,q,17)), acc[17]); \
    acc[18] = fmaf(iv, WC(EIDX(p,q,18)), acc[18]); \
    acc[19] = fmaf(iv, WC(EIDX(p,q,19)), acc[19]); \
    acc[20] = fmaf(iv, WC(EIDX(p,q,20)), acc[20]); } while (0)

#define PHASE(p, REFILL, NEXTIM) do { \
    float4 imn = im; \
    if (NEXTIM) imn = *reinterpret_cast<const float4*>(&ir[(base4 + (p) + 1) * 4]); \
    FMA21(p,0); FMA21(p,1); FMA21(p,2); FMA21(p,3); \
    if (REFILL) { \
        float4 nw = *reinterpret_cast<const float4*>(&tr[(base4 + (p) + 6) * 4]); \
        if ((p)%6==0) w0=nw; else if ((p)%6==1) w1=nw; else if ((p)%6==2) w2=nw; \
        else if ((p)%6==3) w3=nw; else if ((p)%6==4) w4=nw; else w5=nw; \
    } \
    im = imn; \
} while (0)

__global__ __launch_bounds__(256) void k_corr(const float* __restrict__ fr,
                                              const float* __restrict__ tp,
                                              const float* __restrict__ scal,
                                              float* __restrict__ cp) {
    __shared__ __align__(16) float smem[TROWS * TSTR + RB * ISTR];  // 47808 B
    float* t_s = smem;
    float* i_s = smem + TROWS * TSTR;
    int tid = threadIdx.x;
    int bid = blockIdx.x;
    int xb = bid >> 3, yb = bid & 7;
    int x0 = xb * RB, y0 = yb * YC;
    float mt = scal[0], mf = scal[1];

    for (int idx = tid; idx < TROWS * TCOLS; idx += 256) {
        int i = idx / TCOLS, j = idx - i * TCOLS;
        int gr = (x0 - 10 + i + HC) & (HC - 1);
        int gc = (y0 - 10 + j + HC) & (HC - 1);
        t_s[i * TSTR + j] = tp[(size_t)(OFF + gr) * H0 + OFF + gc] - mt;
    }
    for (int idx = tid; idx < RB * YC; idx += 256) {
        int i = idx >> 8, j = idx & 255;
        int gr = x0 + i;
        i_s[i * ISTR + j] = (gr < HC) ? fr[(size_t)(OFF + gr) * H0 + OFF + y0 + j] - mf : 0.f;
    }
    __syncthreads();

    float acc[NA];
    int xl = tid / NA, a = tid - xl * NA;
    bool owner = tid < RB * NA;
    bool act = owner && (x0 + xl < HC);
#pragma unroll
    for (int b = 0; b < NA; b++) acc[b] = 0.f;
    if (act) {
        const float* tr = &t_s[(xl + 20 - a) * TSTR];
        const float* ir = &i_s[xl * ISTR];
        float4 w0, w1, w2, w3, w4, w5;
        w0 = *reinterpret_cast<const float4*>(&tr[0]);
        w1 = *reinterpret_cast<const float4*>(&tr[4]);
        w2 = *reinterpret_cast<const float4*>(&tr[8]);
        w3 = *reinterpret_cast<const float4*>(&tr[12]);
        w4 = *reinterpret_cast<const float4*>(&tr[16]);
        w5 = *reinterpret_cast<const float4*>(&tr[20]);
        float4 im = *reinterpret_cast<const float4*>(&ir[0]);
        int base4 = 0;
        for (int g = 0; g < 10; ++g) {
            PHASE(0,1,1); PHASE(1,1,1); PHASE(2,1,1);
            PHASE(3,1,1); PHASE(4,1,1); PHASE(5,1,1);
            base4 += 6;
        }
        // tail: 16 px (base4 == 60)
        PHASE(0,1,1); PHASE(1,1,1); PHASE(2,1,1); PHASE(3,0,0);
    }
    __syncthreads();                 // done with t_s/i_s; reuse as reduction buffer
    float* red = smem;               // red[(a*21+b)*12 + xl]
    if (owner) {
#pragma unroll
        for (int b = 0; b < NA; b++) red[(a * NA + b) * RB + xl] = acc[b];
    }
    __syncthreads();
    for (int ab = tid; ab < NAB; ab += 256) {
        float s = 0.f;
#pragma unroll
        for (int k = 0; k < RB; k++) s += red[ab * RB + k];
        cp[(size_t)bid * NAB + ab] = s;
    }
}

// ---------------- K5a: deterministic reduction of per-block partials ----------------
__global__ void k_ccreduce(const float* __restrict__ cp, double* __restrict__ ccv) {
    __shared__ double red[256];
    int ab = blockIdx.x, tid = threadIdx.x;
    double s = 0;
    for (int blk = tid; blk < NBLK; blk += 256) s += (double)cp[(size_t)blk * NAB + ab];
    red[tid] = s;
    __syncthreads();
    for (int off = 128; off > 0; off >>= 1) {
        if (tid < off) red[tid] += red[tid + off];
        __syncthreads();
    }
    if (tid == 0) ccv[ab] = red[0];
}

// ---------------- K5b: ncc, argmax (first-max), log-parabola ----------------
__global__ void k_peak(const double* __restrict__ ccv, const float* __restrict__ den,
                       float* __restrict__ scal, float* __restrict__ out) {
    __shared__ float ncc[NAB];
    __shared__ float bv[512];
    __shared__ int bi_[512];
    int tid = threadIdx.x;
    if (tid < NAB) {
        float c = fabsf((float)ccv[tid]);
        float v = c / den[tid];
        if (v != v) v = 0.f;
        ncc[tid] = v;
    }
    __syncthreads();
    bv[tid] = (tid < NAB) ? ncc[tid] : -1e38f;
    bi_[tid] = (tid < NAB) ? tid : 0;
    __syncthreads();
    for (int off = 256; off > 0; off >>= 1) {
        if (tid < off) {
            float v2 = bv[tid + off]; int i2 = bi_[tid + off];
            if (v2 > bv[tid] || (v2 == bv[tid] && i2 < bi_[tid])) { bv[tid] = v2; bi_[tid] = i2; }
        }
        __syncthreads();
    }
    if (tid == 0) {
        int am = bi_[0];
        int sx = am / NA, sy = am - (am / NA) * NA;
        auto L = [&](int i, int j) {
            int ii = ((i % NA) + NA) % NA;
            int jj = ((j % NA) + NA) % NA;
            return logf(ncc[ii * NA + jj]);
        };
        float l0 = L(sx, sy);
        float lxm = L(sx - 1, sy), lxp = L(sx + 1, sy);
        float lym = L(sx, sy - 1), lyp = L(sx, sy + 1);
        float four = 4.f * l0;
        float shx = -(float)(sx - 10) - (lxm - lxp) / (2.f * lxm - four + 2.f * lxp);
        float shy = -(float)(sy - 10) - (lym - lyp) / (2.f * lym - four + 2.f * lyp);
        scal[3] = shx; scal[4] = shy;
        out[(size_t)H0 * H0]     = shx;
        out[(size_t)H0 * H0 + 1] = shy;
    }
}

// ---------------- K6: bilinear translate + transposed flatten ----------------
__global__ __launch_bounds__(256) void k_translate(const float* __restrict__ fr,
                                                   const float* __restrict__ scal,
                                                   float* __restrict__ out) {
    __shared__ float T[65 * 67];
    int tid = threadIdx.x;
    int bx = blockIdx.x % 48, by = blockIdx.x / 48;
    int r0 = bx * 64, c0 = by * 64;
    float dx = scal[3], dy = scal[4];
    float fy = -dy, Fy = floorf(fy), wr = fy - Fy;
    float fx = -dx, Fx = floorf(fx), wc = fx - Fx;
    int R0 = r0 + (int)Fy, C0 = c0 + (int)Fx;
    for (int idx = tid; idx < 65 * 65; idx += 256) {
        int i = idx / 65, j = idx - i * 65;
        int gr = R0 + i, gc = C0 + j;
        float v = 0.f;
        if (gr >= 0 && gr < H0 && gc >= 0 && gc < H0) v = fr[(size_t)gr * H0 + gc];
        T[i * 67 + j] = v;
    }
    __syncthreads();
    float w00 = (1.f - wr) * (1.f - wc), w01 = (1.f - wr) * wc;
    float w10 = wr * (1.f - wc),        w11 = wr * wc;
    int rl = (tid & 15) * 4;
    int cl0 = tid >> 4;
    auto S = [&](int rr, int cl) {
        return w00 * T[rr * 67 + cl] + w01 * T[rr * 67 + cl + 1] +
               w10 * T[(rr + 1) * 67 + cl] + w11 * T[(rr + 1) * 67 + cl + 1];
    };
    for (int q = 0; q < 4; q++) {
        int cl = cl0 + q * 16;
        float4 res = make_float4(S(rl, cl), S(rl + 1, cl), S(rl + 2, cl), S(rl + 3, cl));
        *reinterpret_cast<float4*>(&out[(size_t)(c0 + cl) * H0 + r0 + rl]) = res;
    }
}

extern "C" void kernel_launch(void* const* d_in, const int* in_sizes, int n_in,
                              void* d_out, int out_size, void* d_ws, size_t ws_size,
                              hipStream_t stream) {
    const float* fr = (const float*)d_in[0];
    const float* tp = (const float*)d_in[1];
    float* out = (float*)d_out;
    char* ws = (char*)d_ws;
    float*  scal = (float*)(ws + WS_SCAL);
    double* p1   = (double*)(ws + WS_P1);
    double* TT   = (double*)(ws + WS_TT);
    double* Rv   = (double*)(ws + WS_R);
    double* Rv2  = (double*)(ws + WS_R2);
    float*  den  = (float*)(ws + WS_DEN);
    double* ccv  = (double*)(ws + WS_CCV);
    float*  cp   = (float*)(ws + WS_CP);

    k_sums      <<<512, 256, 0, stream>>>(fr, tp, p1);
    k_sums_final<<<1, 512, 0, stream>>>(p1, scal);
    k_rowpool   <<<2048, 256, 0, stream>>>(fr, Rv, Rv2);
    k_colsum    <<<2 * NA, 256, 0, stream>>>(Rv, Rv2, TT);
    k_den       <<<1, 512, 0, stream>>>(Rv, Rv2, TT, scal, den);
    k_corr      <<<NBLK, 256, 0, stream>>>(fr, tp, scal, cp);
    k_ccreduce  <<<NAB, 256, 0, stream>>>(cp, ccv);
    k_peak      <<<1, 512, 0, stream>>>(ccv, den, scal, out);
    k_translate <<<2304, 256, 0, stream>>>(fr, scal, out);
}

// Round 4
// 101.684 us; speedup vs baseline: 2.1091x; 1.2066x over previous
//
#include <hip/hip_runtime.h>
#include <math.h>

#define H0 3072
#define HC 2048
#define OFF 512
#define NA 21
#define NAB 441
#define KWIN 2028

// ---- k_corr (MFMA) tiling ----
#define TB 32                    // t-rows per block
#define YCB 128                  // y per block
#define NTB 64                   // 2048/TB
#define NYB 16                   // 2048/YCB
#define NBLK (NTB * NYB)         // 1024
#define ILDS_STR 136             // elems (pad: 272B = 17 quads, spread)
#define ILDS_ROWS 63             // TB + 31
#define TLDS_STR 168             // elems per copy row (336B = 21 quads, spread)
#define TCOPY_ELEMS (TB * TLDS_STR)          // 5376
#define TCOPY_WORDS (TCOPY_ELEMS / 2)        // 2688
#define ILDS_BYTES (ILDS_ROWS * ILDS_STR * 2)   // 17136 (mult of 8)
#define TLDS_BYTES (4 * TCOPY_ELEMS * 2)        // 43008

// ws layout (bytes)
#define WS_SCAL 128              // floats: [0]mean_t [1]mean_f [2]t_var [3]sh_x [4]sh_y
#define WS_P1   256              // 512*2 doubles (tp partials)
#define WS_TT   12800            // 42 doubles
#define WS_RS   13312            // 2048 doubles (fr row sums)
#define WS_R    32768            // Rv : [j][x] 21*2048 doubles
#define WS_R2   376832           // Rv2
#define WS_DEN  720896           // 441 floats
#define WS_CCV  724992           // 441 doubles
#define WS_CP   786432           // NBLK*441 floats

typedef __attribute__((ext_vector_type(8))) short short8;
typedef __attribute__((ext_vector_type(4))) float f32x4;

static __device__ __forceinline__ unsigned f2bf_pack(float a, float b) {
    union { float f; unsigned u; } x, y; x.f = a; y.f = b;
    unsigned ra = (x.u + 0x7fff + ((x.u >> 16) & 1)) >> 16;
    unsigned rb = (y.u + 0x7fff + ((y.u >> 16) & 1)) >> 16;
    return ra | (rb << 16);
}

// ---------------- K1: tp sums (fr sum comes from k_rowpool row sums) ----------------
__global__ void k_sums(const float* __restrict__ tp, double* __restrict__ p1) {
    __shared__ double rs[256 * 2];
    double st = 0, st2 = 0;
    const int n = HC * HC;
    for (int i = blockIdx.x * blockDim.x + threadIdx.x; i < n; i += gridDim.x * blockDim.x) {
        int x = i >> 11, y = i & 2047;
        double t = tp[(size_t)(OFF + x) * H0 + OFF + y];
        st += t; st2 += t * t;
    }
    int tid = threadIdx.x;
    rs[tid] = st; rs[256 + tid] = st2;
    __syncthreads();
    for (int off = 128; off > 0; off >>= 1) {
        if (tid < off) { rs[tid] += rs[tid + off]; rs[256 + tid] += rs[256 + tid + off]; }
        __syncthreads();
    }
    if (tid == 0) { p1[blockIdx.x * 2 + 0] = rs[0]; p1[blockIdx.x * 2 + 1] = rs[256]; }
}

__global__ void k_sums_final(const double* __restrict__ p1, const double* __restrict__ rowsum,
                             float* __restrict__ scal) {
    __shared__ double rs[512 * 3];
    int tid = threadIdx.x;
    double sf = rowsum[tid] + rowsum[512 + tid] + rowsum[1024 + tid] + rowsum[1536 + tid];
    rs[tid] = p1[tid * 2 + 0];
    rs[512 + tid] = p1[tid * 2 + 1];
    rs[1024 + tid] = sf;
    __syncthreads();
    for (int off = 256; off > 0; off >>= 1) {
        if (tid < off) {
            rs[tid] += rs[tid + off];
            rs[512 + tid] += rs[512 + tid + off];
            rs[1024 + tid] += rs[1024 + tid + off];
        }
        __syncthreads();
    }
    if (tid == 0) {
        double N = (double)HC * (double)HC;
        double st = rs[0], st2 = rs[512], sfd = rs[1024];
        float mt = (float)(st / N);
        float mf = (float)(sfd / N);
        double m = (double)mt;
        double tv = st2 - 2.0 * m * st + N * m * m;
        scal[0] = mt;
        scal[1] = mf;
        scal[2] = (float)tv + 1e-8f;
    }
}

// ---------------- K2: per-row window sums + raw row sum ----------------
__global__ void k_rowpool(const float* __restrict__ fr,
                          double* __restrict__ Rv, double* __restrict__ Rv2,
                          double* __restrict__ rowsum) {
    __shared__ float row[2048];
    __shared__ double s1[256], s2[256];
    int x = blockIdx.x, tid = threadIdx.x;
    const float* src = fr + (size_t)(OFF + x) * H0 + OFF;
    double a = 0, b = 0;
    for (int k = 0; k < 8; k++) {
        int y = tid + k * 256;
        float v = src[y];
        row[y] = v;
        a += v; b += (double)v * v;
    }
    s1[tid] = a; s2[tid] = b;
    __syncthreads();
    for (int off = 128; off > 0; off >>= 1) {
        if (tid < off) { s1[tid] += s1[tid + off]; s2[tid] += s2[tid + off]; }
        __syncthreads();
    }
    if (tid == 0) rowsum[x] = s1[0];
    if (tid < NA) {
        double h1 = 0, h2 = 0;
        for (int y = 0; y < tid; y++)          { float v = row[y]; h1 += v; h2 += (double)v * v; }
        for (int y = tid + KWIN; y < 2048; y++){ float v = row[y]; h1 += v; h2 += (double)v * v; }
        Rv [(size_t)tid * 2048 + x] = s1[0] - h1;
        Rv2[(size_t)tid * 2048 + x] = s2[0] - h2;
    }
}

// ---------------- K3a: column totals TT[42] ----------------
__global__ void k_colsum(const double* __restrict__ Rv, const double* __restrict__ Rv2,
                         double* __restrict__ TT) {
    __shared__ double red[256];
    int b = blockIdx.x, tid = threadIdx.x;
    const double* R = (b >= NA) ? (Rv2 + (size_t)(b - NA) * 2048)
                                : (Rv  + (size_t)b * 2048);
    double s = 0;
    for (int x = tid; x < 2048; x += 256) s += R[x];
    red[tid] = s;
    __syncthreads();
    for (int off = 128; off > 0; off >>= 1) {
        if (tid < off) red[tid] += red[tid + off];
        __syncthreads();
    }
    if (tid == 0) TT[b] = red[0];
}

// ---------------- K3b: denom[441] ----------------
__global__ void k_den(const double* __restrict__ Rv, const double* __restrict__ Rv2,
                      const double* __restrict__ TT, const float* __restrict__ scal,
                      float* __restrict__ den) {
    int tid = threadIdx.x;
    if (tid >= NAB) return;
    int i = tid / NA, j = tid - (tid / NA) * NA;
    const double* R0 = Rv  + (size_t)j * 2048;
    const double* R1 = Rv2 + (size_t)j * 2048;
    double h0 = 0, h1 = 0;
    for (int x = 0; x < i; x++)           { h0 += R0[x]; h1 += R1[x]; }
    for (int x = i + KWIN; x < 2048; x++) { h0 += R0[x]; h1 += R1[x]; }
    double area = (double)KWIN * (double)KWIN;
    float lm0 = (float)((TT[j] - h0) / area);
    float lm1 = (float)((TT[NA + j] - h1) / area);
    float iv = lm1 - (lm0 * lm0) / 4194304.0f + 1e-8f;
    if (iv < 0.f) iv = 0.f;
    den[tid] = sqrtf(scal[2] * iv);
}

// ---------------- K4: MFMA circular cross-correlation ----------------
// cc[a,b] = sum_t sum_y I[t+a-10, y] * T[t, y-b+10]   (circular, means pre-subtracted)
// GEMM: M=a (2x16 tiles), N=b (2x16), K=(t,y). mfma_f32_16x16x32_bf16.
// A-frag: lane row = l&15, k = 8*(l>>4)+e  -> aligned ds_read_b128 from I_lds.
// B-frag (Toeplitz): 4 parity-shifted T copies in LDS -> two aligned ds_read_b64.
__global__ __launch_bounds__(256) void k_corr(const float* __restrict__ fr,
                                              const float* __restrict__ tp,
                                              const float* __restrict__ scal,
                                              float* __restrict__ cp) {
    __shared__ __align__(16) char smem[ILDS_BYTES + TLDS_BYTES];
    unsigned short* Il = (unsigned short*)smem;
    unsigned short* Tl = (unsigned short*)(smem + ILDS_BYTES);
    unsigned* Iw = (unsigned*)smem;
    unsigned* Tw = (unsigned*)Tl;
    int tid = threadIdx.x;
    int bid = blockIdx.x;
    int t0 = (bid >> 4) * TB;
    int y0 = (bid & 15) * YCB;
    float mt = scal[0], mf = scal[1];

    // stage I: rows t0-10 .. t0+52 (mod 2048), cols [y0, y0+128)
    for (int idx = tid; idx < ILDS_ROWS * 64; idx += 256) {
        int row = idx >> 6, pc = idx & 63;
        int grow = (t0 - 10 + row) & (HC - 1);
        float2 v = *(const float2*)&fr[(size_t)(OFF + grow) * H0 + OFF + y0 + 2 * pc];
        Iw[(row * ILDS_STR >> 1) + pc] = f2bf_pack(v.x - mf, v.y - mf);
    }
    // stage T copy0: row t0+i, cols (y0-22+j) mod 2048, j in [0,168)
    for (int idx = tid; idx < TB * 84; idx += 256) {
        int row = idx / 84, pc = idx - row * 84;
        int gcol = (y0 - 22 + 2 * pc) & (HC - 1);
        float2 v = *(const float2*)&tp[(size_t)(OFF + t0 + row) * H0 + OFF + gcol];
        Tw[row * 84 + pc] = f2bf_pack(v.x - mt, v.y - mt);
    }
    __syncthreads();
    // derive copies 1..3 (copy_c[j] = copy0[j+c])
    for (int idx = tid; idx < TB * 82; idx += 256) {
        int row = idx / 82, k = idx - row * 82;
        unsigned w0 = Tw[row * 84 + k], w1 = Tw[row * 84 + k + 1], w2 = Tw[row * 84 + k + 2];
        Tw[TCOPY_WORDS     + row * 84 + k] = (w0 >> 16) | (w1 << 16);
        Tw[2 * TCOPY_WORDS + row * 84 + k] = w1;
        Tw[3 * TCOPY_WORDS + row * 84 + k] = (w1 >> 16) | (w2 << 16);
    }
    __syncthreads();

    int l = tid & 63, wv = tid >> 6;
    int kg = l >> 4, i16 = l & 15;
    f32x4 acc00 = {0.f, 0.f, 0.f, 0.f};
    f32x4 acc01 = {0.f, 0.f, 0.f, 0.f};
    f32x4 acc10 = {0.f, 0.f, 0.f, 0.f};
    f32x4 acc11 = {0.f, 0.f, 0.f, 0.f};

    for (int dt = 0; dt < 8; ++dt) {
        int t_loc = 8 * wv + dt;
        const unsigned short* Trow = Tl + t_loc * TLDS_STR;
        const unsigned short* Ir0 = Il + (t_loc + i16) * ILDS_STR + 8 * kg;
        const unsigned short* Ir1 = Ir0 + 16 * ILDS_STR;
#pragma unroll
        for (int ks = 0; ks < 4; ++ks) {
            int yk = 32 * ks;
            short8 a0 = *(const short8*)(Ir0 + yk);
            short8 a1 = *(const short8*)(Ir1 + yk);
            union { uint2 u[2]; short8 s; } ub0, ub1;
            {
                int s0 = yk + 8 * kg - i16 + 32;            // nt=0 (n = i16)
                int p = s0 & 3;
                const unsigned short* q = Trow + p * TCOPY_ELEMS + (s0 - p);
                ub0.u[0] = *(const uint2*)q;
                ub0.u[1] = *(const uint2*)(q + 4);
            }
            {
                int s0 = yk + 8 * kg - i16 + 16;            // nt=1 (n = 16+i16)
                int p = s0 & 3;
                const unsigned short* q = Trow + p * TCOPY_ELEMS + (s0 - p);
                ub1.u[0] = *(const uint2*)q;
                ub1.u[1] = *(const uint2*)(q + 4);
            }
            acc00 = __builtin_amdgcn_mfma_f32_16x16x32_bf16(a0, ub0.s, acc00, 0, 0, 0);
            acc01 = __builtin_amdgcn_mfma_f32_16x16x32_bf16(a0, ub1.s, acc01, 0, 0, 0);
            acc10 = __builtin_amdgcn_mfma_f32_16x16x32_bf16(a1, ub0.s, acc10, 0, 0, 0);
            acc11 = __builtin_amdgcn_mfma_f32_16x16x32_bf16(a1, ub1.s, acc11, 0, 0, 0);
        }
    }

    __syncthreads();                    // all waves done with I/T LDS
    float* buf = (float*)smem;          // 4 waves x 32x32 f32 = 16 KB (fits I region)
    {
        int r0w = 4 * kg;
#pragma unroll
        for (int r = 0; r < 4; ++r) {
            buf[wv * 1024 + (r0w + r) * 32 + i16]        = acc00[r];
            buf[wv * 1024 + (r0w + r) * 32 + 16 + i16]   = acc01[r];
            buf[wv * 1024 + (16 + r0w + r) * 32 + i16]      = acc10[r];
            buf[wv * 1024 + (16 + r0w + r) * 32 + 16 + i16] = acc11[r];
        }
    }
    __syncthreads();
    for (int e = tid; e < 1024; e += 256) {
        int a = e >> 5, b = e & 31;
        if (a < NA && b < NA)
            cp[(size_t)bid * NAB + a * NA + b] =
                buf[e] + buf[1024 + e] + buf[2048 + e] + buf[3072 + e];
    }
}

// ---------------- K5a: deterministic reduction of per-block partials ----------------
__global__ void k_ccreduce(const float* __restrict__ cp, double* __restrict__ ccv) {
    __shared__ double red[256];
    int ab = blockIdx.x, tid = threadIdx.x;
    double s = 0;
    for (int blk = tid; blk < NBLK; blk += 256) s += (double)cp[(size_t)blk * NAB + ab];
    red[tid] = s;
    __syncthreads();
    for (int off = 128; off > 0; off >>= 1) {
        if (tid < off) red[tid] += red[tid + off];
        __syncthreads();
    }
    if (tid == 0) ccv[ab] = red[0];
}

// ---------------- K5b: ncc, argmax (first-max), log-parabola ----------------
__global__ void k_peak(const double* __restrict__ ccv, const float* __restrict__ den,
                       float* __restrict__ scal, float* __restrict__ out) {
    __shared__ float ncc[NAB];
    __shared__ float bv[512];
    __shared__ int bi_[512];
    int tid = threadIdx.x;
    if (tid < NAB) {
        float c = fabsf((float)ccv[tid]);
        float v = c / den[tid];
        if (v != v) v = 0.f;
        ncc[tid] = v;
    }
    __syncthreads();
    bv[tid] = (tid < NAB) ? ncc[tid] : -1e38f;
    bi_[tid] = (tid < NAB) ? tid : 0;
    __syncthreads();
    for (int off = 256; off > 0; off >>= 1) {
        if (tid < off) {
            float v2 = bv[tid + off]; int i2 = bi_[tid + off];
            if (v2 > bv[tid] || (v2 == bv[tid] && i2 < bi_[tid])) { bv[tid] = v2; bi_[tid] = i2; }
        }
        __syncthreads();
    }
    if (tid == 0) {
        int am = bi_[0];
        int sx = am / NA, sy = am - (am / NA) * NA;
        auto L = [&](int i, int j) {
            int ii = ((i % NA) + NA) % NA;
            int jj = ((j % NA) + NA) % NA;
            return logf(ncc[ii * NA + jj]);
        };
        float l0 = L(sx, sy);
        float lxm = L(sx - 1, sy), lxp = L(sx + 1, sy);
        float lym = L(sx, sy - 1), lyp = L(sx, sy + 1);
        float four = 4.f * l0;
        float shx = -(float)(sx - 10) - (lxm - lxp) / (2.f * lxm - four + 2.f * lxp);
        float shy = -(float)(sy - 10) - (lym - lyp) / (2.f * lym - four + 2.f * lyp);
        scal[3] = shx; scal[4] = shy;
        out[(size_t)H0 * H0]     = shx;
        out[(size_t)H0 * H0 + 1] = shy;
    }
}

// ---------------- K6: bilinear translate + transposed flatten ----------------
__global__ __launch_bounds__(256) void k_translate(const float* __restrict__ fr,
                                                   const float* __restrict__ scal,
                                                   float* __restrict__ out) {
    __shared__ float T[65 * 67];
    int tid = threadIdx.x;
    int bx = blockIdx.x % 48, by = blockIdx.x / 48;
    int r0 = bx * 64, c0 = by * 64;
    float dx = scal[3], dy = scal[4];
    float fy = -dy, Fy = floorf(fy), wr = fy - Fy;
    float fx = -dx, Fx = floorf(fx), wc = fx - Fx;
    int R0 = r0 + (int)Fy, C0 = c0 + (int)Fx;
    for (int idx = tid; idx < 65 * 65; idx += 256) {
        int i = idx / 65, j = idx - i * 65;
        int gr = R0 + i, gc = C0 + j;
        float v = 0.f;
        if (gr >= 0 && gr < H0 && gc >= 0 && gc < H0) v = fr[(size_t)gr * H0 + gc];
        T[i * 67 + j] = v;
    }
    __syncthreads();
    float w00 = (1.f - wr) * (1.f - wc), w01 = (1.f - wr) * wc;
    float w10 = wr * (1.f - wc),        w11 = wr * wc;
    int rl = (tid & 15) * 4;
    int cl0 = tid >> 4;
    auto S = [&](int rr, int cl) {
        return w00 * T[rr * 67 + cl] + w01 * T[rr * 67 + cl + 1] +
               w10 * T[(rr + 1) * 67 + cl] + w11 * T[(rr + 1) * 67 + cl + 1];
    };
    for (int q = 0; q < 4; q++) {
        int cl = cl0 + q * 16;
        float4 res = make_float4(S(rl, cl), S(rl + 1, cl), S(rl + 2, cl), S(rl + 3, cl));
        *reinterpret_cast<float4*>(&out[(size_t)(c0 + cl) * H0 + r0 + rl]) = res;
    }
}

extern "C" void kernel_launch(void* const* d_in, const int* in_sizes, int n_in,
                              void* d_out, int out_size, void* d_ws, size_t ws_size,
                              hipStream_t stream) {
    const float* fr = (const float*)d_in[0];
    const float* tp = (const float*)d_in[1];
    float* out = (float*)d_out;
    char* ws = (char*)d_ws;
    float*  scal = (float*)(ws + WS_SCAL);
    double* p1   = (double*)(ws + WS_P1);
    double* TT   = (double*)(ws + WS_TT);
    double* rsum = (double*)(ws + WS_RS);
    double* Rv   = (double*)(ws + WS_R);
    double* Rv2  = (double*)(ws + WS_R2);
    float*  den  = (float*)(ws + WS_DEN);
    double* ccv  = (double*)(ws + WS_CCV);
    float*  cp   = (float*)(ws + WS_CP);

    k_rowpool   <<<2048, 256, 0, stream>>>(fr, Rv, Rv2, rsum);
    k_sums      <<<512, 256, 0, stream>>>(tp, p1);
    k_sums_final<<<1, 512, 0, stream>>>(p1, rsum, scal);
    k_colsum    <<<2 * NA, 256, 0, stream>>>(Rv, Rv2, TT);
    k_den       <<<1, 512, 0, stream>>>(Rv, Rv2, TT, scal, den);
    k_corr      <<<NBLK, 256, 0, stream>>>(fr, tp, scal, cp);
    k_ccreduce  <<<NAB, 256, 0, stream>>>(cp, ccv);
    k_peak      <<<1, 512, 0, stream>>>(ccv, den, scal, out);
    k_translate <<<2304, 256, 0, stream>>>(fr, scal, out);
}

// Round 5
// 83.655 us; speedup vs baseline: 2.5636x; 1.2155x over previous
//
#include <hip/hip_runtime.h>
#include <math.h>

#define H0 3072
#define HC 2048
#define OFF 512
#define NA 21
#define NAB 441
#define KWIN 2028

// ---- k_corr (MFMA) tiling ----
#define TB 32                    // t-rows per block
#define YCB 128                  // y per block
#define NTB 64                   // 2048/TB
#define NYB 16                   // 2048/YCB
#define NBLK (NTB * NYB)         // 1024
#define ILDS_STR 136             // elems
#define ILDS_ROWS 63             // TB + 31
#define ILDS_BYTES (ILDS_ROWS * ILDS_STR * 2)   // 17136
// T: 4 parity-shifted copies, per-copy 32 rows x 176 elems, +8dw stagger per copy
#define T_ROWE 176               // elems per row
#define T_ROWW 88                // dwords per row
#define CSTR_DW 2824             // 32*88 + 8 (stagger: 2824%32 == 8)
#define CSTR_E  5648
#define TLDS_BYTES (4 * CSTR_DW * 4)            // 45184
// total smem = 62320

// ws layout (bytes)
#define WS_SCAL 128              // floats: [0]mean_t [1]mean_f [2]t_var [3]sh_x [4]sh_y
#define WS_P1   256              // 512*2 doubles (tp partials)
#define WS_TT   12800            // 42 doubles
#define WS_RS   13312            // 2048 doubles (fr row sums)
#define WS_R    32768            // Rv : [j][x] 21*2048 doubles
#define WS_R2   376832           // Rv2
#define WS_DEN  720896           // 441 floats
#define WS_CCV  724992           // 441 doubles
#define WS_CP   786432           // NBLK*441 floats

typedef __attribute__((ext_vector_type(8))) short short8;
typedef __attribute__((ext_vector_type(4))) float f32x4;

static __device__ __forceinline__ unsigned f2bf_pack(float a, float b) {
    union { float f; unsigned u; } x, y; x.f = a; y.f = b;
    unsigned ra = (x.u + 0x7fff + ((x.u >> 16) & 1)) >> 16;
    unsigned rb = (y.u + 0x7fff + ((y.u >> 16) & 1)) >> 16;
    return ra | (rb << 16);
}

// ---------------- K1: tp sums ----------------
__global__ void k_sums(const float* __restrict__ tp, double* __restrict__ p1) {
    __shared__ double rs[8];
    double st = 0, st2 = 0;
    const int n4 = (HC * HC) / 4;
    for (int i = blockIdx.x * blockDim.x + threadIdx.x; i < n4; i += gridDim.x * blockDim.x) {
        int x = i >> 9, y4 = (i & 511) * 4;
        float4 t4 = *(const float4*)&tp[(size_t)(OFF + x) * H0 + OFF + y4];
        st += ((double)t4.x + t4.y) + ((double)t4.z + t4.w);
        st2 += ((double)t4.x * t4.x + (double)t4.y * t4.y) +
               ((double)t4.z * t4.z + (double)t4.w * t4.w);
    }
    int tid = threadIdx.x;
    for (int o = 32; o > 0; o >>= 1) { st += __shfl_down(st, o); st2 += __shfl_down(st2, o); }
    if ((tid & 63) == 0) { rs[tid >> 6] = st; rs[4 + (tid >> 6)] = st2; }
    __syncthreads();
    if (tid == 0) {
        p1[blockIdx.x * 2 + 0] = rs[0] + rs[1] + rs[2] + rs[3];
        p1[blockIdx.x * 2 + 1] = rs[4] + rs[5] + rs[6] + rs[7];
    }
}

__global__ void k_sums_final(const double* __restrict__ p1, const double* __restrict__ rowsum,
                             float* __restrict__ scal) {
    __shared__ double rs[512 * 3];
    int tid = threadIdx.x;
    double sf = rowsum[tid] + rowsum[512 + tid] + rowsum[1024 + tid] + rowsum[1536 + tid];
    rs[tid] = p1[tid * 2 + 0];
    rs[512 + tid] = p1[tid * 2 + 1];
    rs[1024 + tid] = sf;
    __syncthreads();
    for (int off = 256; off > 0; off >>= 1) {
        if (tid < off) {
            rs[tid] += rs[tid + off];
            rs[512 + tid] += rs[512 + tid + off];
            rs[1024 + tid] += rs[1024 + tid + off];
        }
        __syncthreads();
    }
    if (tid == 0) {
        double N = (double)HC * (double)HC;
        double st = rs[0], st2 = rs[512], sfd = rs[1024];
        float mt = (float)(st / N);
        float mf = (float)(sfd / N);
        double m = (double)mt;
        double tv = st2 - 2.0 * m * st + N * m * m;
        scal[0] = mt;
        scal[1] = mf;
        scal[2] = (float)tv + 1e-8f;
    }
}

// ---------------- K2: per-row window sums + raw row sum ----------------
__global__ void k_rowpool(const float* __restrict__ fr,
                          double* __restrict__ Rv, double* __restrict__ Rv2,
                          double* __restrict__ rowsum) {
    __shared__ float row[2048];
    __shared__ double s1[8], s2[8];
    int x = blockIdx.x, tid = threadIdx.x;
    const float* src = fr + (size_t)(OFF + x) * H0 + OFF;
    float4 v0 = *(const float4*)&src[4 * tid];
    float4 v1 = *(const float4*)&src[4 * tid + 1024];
    *(float4*)&row[4 * tid] = v0;
    *(float4*)&row[4 * tid + 1024] = v1;
    double a = ((double)v0.x + v0.y) + ((double)v0.z + v0.w) +
               ((double)v1.x + v1.y) + ((double)v1.z + v1.w);
    double b = ((double)v0.x * v0.x + (double)v0.y * v0.y) +
               ((double)v0.z * v0.z + (double)v0.w * v0.w) +
               ((double)v1.x * v1.x + (double)v1.y * v1.y) +
               ((double)v1.z * v1.z + (double)v1.w * v1.w);
    for (int o = 32; o > 0; o >>= 1) { a += __shfl_down(a, o); b += __shfl_down(b, o); }
    if ((tid & 63) == 0) { s1[tid >> 6] = a; s2[tid >> 6] = b; }
    __syncthreads();
    if (tid == 0) {
        double A = s1[0] + s1[1] + s1[2] + s1[3];
        double B = s2[0] + s2[1] + s2[2] + s2[3];
        rowsum[x] = A;
        s1[0] = A; s2[0] = B;
    }
    __syncthreads();
    if (tid < NA) {
        double h1 = 0, h2 = 0;
        for (int y = 0; y < tid; y++)          { float v = row[y]; h1 += v; h2 += (double)v * v; }
        for (int y = tid + KWIN; y < 2048; y++){ float v = row[y]; h1 += v; h2 += (double)v * v; }
        Rv [(size_t)tid * 2048 + x] = s1[0] - h1;
        Rv2[(size_t)tid * 2048 + x] = s2[0] - h2;
    }
}

// ---------------- K3a: column totals TT[42] ----------------
__global__ void k_colsum(const double* __restrict__ Rv, const double* __restrict__ Rv2,
                         double* __restrict__ TT) {
    __shared__ double red[256];
    int b = blockIdx.x, tid = threadIdx.x;
    const double* R = (b >= NA) ? (Rv2 + (size_t)(b - NA) * 2048)
                                : (Rv  + (size_t)b * 2048);
    double s = 0;
    for (int x = tid; x < 2048; x += 256) s += R[x];
    red[tid] = s;
    __syncthreads();
    for (int off = 128; off > 0; off >>= 1) {
        if (tid < off) red[tid] += red[tid + off];
        __syncthreads();
    }
    if (tid == 0) TT[b] = red[0];
}

// ---------------- K3b: denom[441] ----------------
__global__ void k_den(const double* __restrict__ Rv, const double* __restrict__ Rv2,
                      const double* __restrict__ TT, const float* __restrict__ scal,
                      float* __restrict__ den) {
    int tid = threadIdx.x;
    if (tid >= NAB) return;
    int i = tid / NA, j = tid - (tid / NA) * NA;
    const double* R0 = Rv  + (size_t)j * 2048;
    const double* R1 = Rv2 + (size_t)j * 2048;
    double h0 = 0, h1 = 0;
    for (int x = 0; x < i; x++)           { h0 += R0[x]; h1 += R1[x]; }
    for (int x = i + KWIN; x < 2048; x++) { h0 += R0[x]; h1 += R1[x]; }
    double area = (double)KWIN * (double)KWIN;
    float lm0 = (float)((TT[j] - h0) / area);
    float lm1 = (float)((TT[NA + j] - h1) / area);
    float iv = lm1 - (lm0 * lm0) / 4194304.0f + 1e-8f;
    if (iv < 0.f) iv = 0.f;
    den[tid] = sqrtf(scal[2] * iv);
}

// ---------------- K4: MFMA circular cross-correlation ----------------
// cc[a,b] = sum_t sum_y I[t+a-10, y] * T[t, y-b+10]  (circular, means pre-subtracted)
// A-frag (I): aligned ds_read_b128. B-frag (T, Toeplitz): 4 parity copies,
// bank-staggered by 8 dwords each; copies derived in REGISTERS during staging.
__global__ __launch_bounds__(256) void k_corr(const float* __restrict__ fr,
                                              const float* __restrict__ tp,
                                              const float* __restrict__ scal,
                                              float* __restrict__ cp) {
    __shared__ __align__(16) char smem[ILDS_BYTES + TLDS_BYTES];
    unsigned short* Il = (unsigned short*)smem;
    unsigned short* Tl = (unsigned short*)(smem + ILDS_BYTES);
    unsigned* Iw = (unsigned*)smem;
    unsigned* Tw = (unsigned*)Tl;
    int tid = threadIdx.x;
    int bid = blockIdx.x;
    int t0 = (bid >> 4) * TB;
    int y0 = (bid & 15) * YCB;
    float mt = scal[0], mf = scal[1];

    // stage I: rows t0-10 .. t0+52 (mod 2048), cols [y0, y0+128), float4 loads
    for (int idx = tid; idx < ILDS_ROWS * 32; idx += 256) {
        int row = idx >> 5, pc4 = idx & 31;
        int grow = (t0 - 10 + row) & (HC - 1);
        float4 v = *(const float4*)&fr[(size_t)(OFF + grow) * H0 + OFF + y0 + 4 * pc4];
        uint2 pk;
        pk.x = f2bf_pack(v.x - mf, v.y - mf);
        pk.y = f2bf_pack(v.z - mf, v.w - mf);
        *(uint2*)(Iw + row * (ILDS_STR / 2) + 2 * pc4) = pk;
    }
    // stage T + derive 4 parity copies in registers.
    // region elem j <-> T[t0+row, (y0-24+j) mod 2048], j in [0,176)
    for (int u = tid; u < TB * 11; u += 256) {
        int row = u / 11, k = u - row * 11;
        int e0 = 16 * k;
        const float* srcT = tp + (size_t)(OFF + t0 + row) * H0 + OFF;
        unsigned w[10];
#pragma unroll
        for (int q4 = 0; q4 < 5; ++q4) {
            int gcol = (y0 - 24 + e0 + 4 * q4) & (HC - 1);
            float4 v = *(const float4*)&srcT[gcol];
            w[2 * q4]     = f2bf_pack(v.x - mt, v.y - mt);
            w[2 * q4 + 1] = f2bf_pack(v.z - mt, v.w - mt);
        }
        unsigned* dst = Tw + row * T_ROWW + 8 * k;
        uint4 c0a = {w[0], w[1], w[2], w[3]};
        uint4 c0b = {w[4], w[5], w[6], w[7]};
        *(uint4*)(dst) = c0a;
        *(uint4*)(dst + 4) = c0b;
        unsigned d1[8], d2[8], d3[8];
#pragma unroll
        for (int j = 0; j < 8; ++j) {
            d1[j] = (w[j] >> 16) | (w[j + 1] << 16);
            d2[j] = w[j + 1];
            d3[j] = (w[j + 1] >> 16) | (w[j + 2] << 16);
        }
        uint4 c1a = {d1[0], d1[1], d1[2], d1[3]}, c1b = {d1[4], d1[5], d1[6], d1[7]};
        uint4 c2a = {d2[0], d2[1], d2[2], d2[3]}, c2b = {d2[4], d2[5], d2[6], d2[7]};
        uint4 c3a = {d3[0], d3[1], d3[2], d3[3]}, c3b = {d3[4], d3[5], d3[6], d3[7]};
        *(uint4*)(dst + CSTR_DW) = c1a;     *(uint4*)(dst + CSTR_DW + 4) = c1b;
        *(uint4*)(dst + 2 * CSTR_DW) = c2a; *(uint4*)(dst + 2 * CSTR_DW + 4) = c2b;
        *(uint4*)(dst + 3 * CSTR_DW) = c3a; *(uint4*)(dst + 3 * CSTR_DW + 4) = c3b;
    }
    __syncthreads();

    int l = tid & 63, wv = tid >> 6;
    int kg = l >> 4, i16 = l & 15;
    f32x4 acc00 = {0.f, 0.f, 0.f, 0.f};
    f32x4 acc01 = {0.f, 0.f, 0.f, 0.f};
    f32x4 acc10 = {0.f, 0.f, 0.f, 0.f};
    f32x4 acc11 = {0.f, 0.f, 0.f, 0.f};

    for (int dt = 0; dt < 8; ++dt) {
        int t_loc = 8 * wv + dt;
        const unsigned short* Trow = Tl + t_loc * T_ROWE;
        const unsigned short* Ir0 = Il + (t_loc + i16) * ILDS_STR;
        const unsigned short* Ir1 = Ir0 + 16 * ILDS_STR;
#pragma unroll
        for (int ks = 0; ks < 4; ++ks) {
            int yk = 32 * ks + 8 * kg;
            short8 a0 = *(const short8*)(Ir0 + yk);
            short8 a1 = *(const short8*)(Ir1 + yk);
            union { uint2 u[2]; short8 s; } ub0, ub1;
            {
                int s0 = yk - i16 + 34;                 // nt=0 (b = i16)
                int c = s0 & 3;
                const unsigned short* q = Trow + c * CSTR_E + (s0 - c);
                ub0.u[0] = *(const uint2*)q;
                ub0.u[1] = *(const uint2*)(q + 4);
            }
            {
                int s0 = yk - i16 + 18;                 // nt=1 (b = 16+i16)
                int c = s0 & 3;
                const unsigned short* q = Trow + c * CSTR_E + (s0 - c);
                ub1.u[0] = *(const uint2*)q;
                ub1.u[1] = *(const uint2*)(q + 4);
            }
            acc00 = __builtin_amdgcn_mfma_f32_16x16x32_bf16(a0, ub0.s, acc00, 0, 0, 0);
            acc01 = __builtin_amdgcn_mfma_f32_16x16x32_bf16(a0, ub1.s, acc01, 0, 0, 0);
            acc10 = __builtin_amdgcn_mfma_f32_16x16x32_bf16(a1, ub0.s, acc10, 0, 0, 0);
            acc11 = __builtin_amdgcn_mfma_f32_16x16x32_bf16(a1, ub1.s, acc11, 0, 0, 0);
        }
    }

    __syncthreads();                    // all waves done with I/T LDS
    float* buf = (float*)smem;          // 4 waves x 32x32 f32 = 16 KB
    {
        int r0w = 4 * kg;
#pragma unroll
        for (int r = 0; r < 4; ++r) {
            buf[wv * 1024 + (r0w + r) * 32 + i16]           = acc00[r];
            buf[wv * 1024 + (r0w + r) * 32 + 16 + i16]      = acc01[r];
            buf[wv * 1024 + (16 + r0w + r) * 32 + i16]      = acc10[r];
            buf[wv * 1024 + (16 + r0w + r) * 32 + 16 + i16] = acc11[r];
        }
    }
    __syncthreads();
    for (int e = tid; e < 1024; e += 256) {
        int a = e >> 5, b = e & 31;
        if (a < NA && b < NA)
            cp[(size_t)bid * NAB + a * NA + b] =
                buf[e] + buf[1024 + e] + buf[2048 + e] + buf[3072 + e];
    }
}

// ---------------- K5a: deterministic reduction of per-block partials ----------------
__global__ void k_ccreduce(const float* __restrict__ cp, double* __restrict__ ccv) {
    __shared__ double red[256];
    int ab = blockIdx.x, tid = threadIdx.x;
    double s = 0;
    for (int blk = tid; blk < NBLK; blk += 256) s += (double)cp[(size_t)blk * NAB + ab];
    red[tid] = s;
    __syncthreads();
    for (int off = 128; off > 0; off >>= 1) {
        if (tid < off) red[tid] += red[tid + off];
        __syncthreads();
    }
    if (tid == 0) ccv[ab] = red[0];
}

// ---------------- K5b: ncc, argmax (first-max), log-parabola ----------------
__global__ void k_peak(const double* __restrict__ ccv, const float* __restrict__ den,
                       float* __restrict__ scal, float* __restrict__ out) {
    __shared__ float ncc[NAB];
    __shared__ float bv[512];
    __shared__ int bi_[512];
    int tid = threadIdx.x;
    if (tid < NAB) {
        float c = fabsf((float)ccv[tid]);
        float v = c / den[tid];
        if (v != v) v = 0.f;
        ncc[tid] = v;
    }
    __syncthreads();
    bv[tid] = (tid < NAB) ? ncc[tid] : -1e38f;
    bi_[tid] = (tid < NAB) ? tid : 0;
    __syncthreads();
    for (int off = 256; off > 0; off >>= 1) {
        if (tid < off) {
            float v2 = bv[tid + off]; int i2 = bi_[tid + off];
            if (v2 > bv[tid] || (v2 == bv[tid] && i2 < bi_[tid])) { bv[tid] = v2; bi_[tid] = i2; }
        }
        __syncthreads();
    }
    if (tid == 0) {
        int am = bi_[0];
        int sx = am / NA, sy = am - (am / NA) * NA;
        auto L = [&](int i, int j) {
            int ii = ((i % NA) + NA) % NA;
            int jj = ((j % NA) + NA) % NA;
            return logf(ncc[ii * NA + jj]);
        };
        float l0 = L(sx, sy);
        float lxm = L(sx - 1, sy), lxp = L(sx + 1, sy);
        float lym = L(sx, sy - 1), lyp = L(sx, sy + 1);
        float four = 4.f * l0;
        float shx = -(float)(sx - 10) - (lxm - lxp) / (2.f * lxm - four + 2.f * lxp);
        float shy = -(float)(sy - 10) - (lym - lyp) / (2.f * lym - four + 2.f * lyp);
        scal[3] = shx; scal[4] = shy;
        out[(size_t)H0 * H0]     = shx;
        out[(size_t)H0 * H0 + 1] = shy;
    }
}

// ---------------- K6: bilinear translate + transposed flatten ----------------
__global__ __launch_bounds__(256) void k_translate(const float* __restrict__ fr,
                                                   const float* __restrict__ scal,
                                                   float* __restrict__ out) {
    __shared__ float T[65 * 67];
    int tid = threadIdx.x;
    int bx = blockIdx.x % 48, by = blockIdx.x / 48;
    int r0 = bx * 64, c0 = by * 64;
    float dx = scal[3], dy = scal[4];
    float fy = -dy, Fy = floorf(fy), wr = fy - Fy;
    float fx = -dx, Fx = floorf(fx), wc = fx - Fx;
    int R0 = r0 + (int)Fy, C0 = c0 + (int)Fx;
    for (int idx = tid; idx < 65 * 65; idx += 256) {
        int i = idx / 65, j = idx - i * 65;
        int gr = R0 + i, gc = C0 + j;
        float v = 0.f;
        if (gr >= 0 && gr < H0 && gc >= 0 && gc < H0) v = fr[(size_t)gr * H0 + gc];
        T[i * 67 + j] = v;
    }
    __syncthreads();
    float w00 = (1.f - wr) * (1.f - wc), w01 = (1.f - wr) * wc;
    float w10 = wr * (1.f - wc),        w11 = wr * wc;
    int rl = (tid & 15) * 4;
    int cl0 = tid >> 4;
    auto S = [&](int rr, int cl) {
        return w00 * T[rr * 67 + cl] + w01 * T[rr * 67 + cl + 1] +
               w10 * T[(rr + 1) * 67 + cl] + w11 * T[(rr + 1) * 67 + cl + 1];
    };
    for (int q = 0; q < 4; q++) {
        int cl = cl0 + q * 16;
        float4 res = make_float4(S(rl, cl), S(rl + 1, cl), S(rl + 2, cl), S(rl + 3, cl));
        *reinterpret_cast<float4*>(&out[(size_t)(c0 + cl) * H0 + r0 + rl]) = res;
    }
}

extern "C" void kernel_launch(void* const* d_in, const int* in_sizes, int n_in,
                              void* d_out, int out_size, void* d_ws, size_t ws_size,
                              hipStream_t stream) {
    const float* fr = (const float*)d_in[0];
    const float* tp = (const float*)d_in[1];
    float* out = (float*)d_out;
    char* ws = (char*)d_ws;
    float*  scal = (float*)(ws + WS_SCAL);
    double* p1   = (double*)(ws + WS_P1);
    double* TT   = (double*)(ws + WS_TT);
    double* rsum = (double*)(ws + WS_RS);
    double* Rv   = (double*)(ws + WS_R);
    double* Rv2  = (double*)(ws + WS_R2);
    float*  den  = (float*)(ws + WS_DEN);
    double* ccv  = (double*)(ws + WS_CCV);
    float*  cp   = (float*)(ws + WS_CP);

    k_rowpool   <<<2048, 256, 0, stream>>>(fr, Rv, Rv2, rsum);
    k_sums      <<<512, 256, 0, stream>>>(tp, p1);
    k_sums_final<<<1, 512, 0, stream>>>(p1, rsum, scal);
    k_colsum    <<<2 * NA, 256, 0, stream>>>(Rv, Rv2, TT);
    k_den       <<<1, 512, 0, stream>>>(Rv, Rv2, TT, scal, den);
    k_corr      <<<NBLK, 256, 0, stream>>>(fr, tp, scal, cp);
    k_ccreduce  <<<NAB, 256, 0, stream>>>(cp, ccv);
    k_peak      <<<1, 512, 0, stream>>>(ccv, den, scal, out);
    k_translate <<<2304, 256, 0, stream>>>(fr, scal, out);
}

// Round 6
// 71.161 us; speedup vs baseline: 3.0138x; 1.1756x over previous
//
#include <hip/hip_runtime.h>
#include <math.h>

#define H0 3072
#define HC 2048
#define OFF 512
#define NA 21
#define NAB 441
#define KWIN 2028

// ---- k_corr (MFMA) tiling ----
#define TCH 64                   // t-rows per block (2 sub-tiles of 32)
#define YCB 128                  // y per block
#define NTB 32                   // 2048/TCH
#define NYB 16                   // 2048/YCB
#define NBLK (NTB * NYB)         // 512
#define ILDS_STR 136             // elems
#define ILDS_ROWS 95             // TCH + 31
#define ILDS_BYTES (ILDS_ROWS * ILDS_STR * 2)   // 25840
// T: 4 parity-shifted copies, per-copy 32 rows x 176 elems, +8dw stagger per copy
#define T_ROWE 176               // elems per row
#define T_ROWW 88                // dwords per row
#define CSTR_DW 2824             // 32*88 + 8 (stagger: 2824%32 == 8)
#define CSTR_E  5648
#define TLDS_BYTES (4 * CSTR_DW * 4)            // 45184
// total smem = 71024 B -> 2 blocks/CU (142KB of 160KB)

// ws layout (bytes)
#define WS_SCAL 128              // floats: [0]mean_t [1]mean_f [2]t_var [3]sh_x [4]sh_y
#define WS_P1   4096             // 2048*2 doubles (per-row tp sums)
#define WS_RS   36864            // 2048 doubles (fr row sums)
#define WS_R    65536            // Rv : [j][x] 21*2048 doubles
#define WS_R2   409600           // Rv2
#define WS_DEN  753664           // 441 floats
#define WS_CCV  757760           // 441 doubles
#define WS_CP   786432           // NBLK*441 floats

typedef __attribute__((ext_vector_type(8))) short short8;
typedef __attribute__((ext_vector_type(4))) float f32x4;

static __device__ __forceinline__ unsigned f2bf_pack(float a, float b) {
    union { float f; unsigned u; } x, y; x.f = a; y.f = b;
    unsigned ra = (x.u + 0x7fff + ((x.u >> 16) & 1)) >> 16;
    unsigned rb = (y.u + 0x7fff + ((y.u >> 16) & 1)) >> 16;
    return ra | (rb << 16);
}

// ---------------- K1: fr row sums + window sums + tp row sums (fused) ----------------
__global__ __launch_bounds__(256) void k_rowpool(const float* __restrict__ fr,
                          const float* __restrict__ tp,
                          double* __restrict__ Rv, double* __restrict__ Rv2,
                          double* __restrict__ rowsum, double* __restrict__ p1) {
    __shared__ float row[2048];
    __shared__ double s1[4], s2[4], s3[4], s4[4];
    int x = blockIdx.x, tid = threadIdx.x;
    const float* srcF = fr + (size_t)(OFF + x) * H0 + OFF;
    const float* srcT = tp + (size_t)(OFF + x) * H0 + OFF;
    float4 v0 = *(const float4*)&srcF[4 * tid];
    float4 v1 = *(const float4*)&srcF[4 * tid + 1024];
    *(float4*)&row[4 * tid] = v0;
    *(float4*)&row[4 * tid + 1024] = v1;
    double a = ((double)v0.x + v0.y) + ((double)v0.z + v0.w) +
               ((double)v1.x + v1.y) + ((double)v1.z + v1.w);
    double b = ((double)v0.x * v0.x + (double)v0.y * v0.y) +
               ((double)v0.z * v0.z + (double)v0.w * v0.w) +
               ((double)v1.x * v1.x + (double)v1.y * v1.y) +
               ((double)v1.z * v1.z + (double)v1.w * v1.w);
    float4 t0 = *(const float4*)&srcT[4 * tid];
    float4 t1 = *(const float4*)&srcT[4 * tid + 1024];
    double st = ((double)t0.x + t0.y) + ((double)t0.z + t0.w) +
                ((double)t1.x + t1.y) + ((double)t1.z + t1.w);
    double st2 = ((double)t0.x * t0.x + (double)t0.y * t0.y) +
                 ((double)t0.z * t0.z + (double)t0.w * t0.w) +
                 ((double)t1.x * t1.x + (double)t1.y * t1.y) +
                 ((double)t1.z * t1.z + (double)t1.w * t1.w);
    for (int o = 32; o > 0; o >>= 1) {
        a += __shfl_down(a, o); b += __shfl_down(b, o);
        st += __shfl_down(st, o); st2 += __shfl_down(st2, o);
    }
    if ((tid & 63) == 0) {
        int w = tid >> 6;
        s1[w] = a; s2[w] = b; s3[w] = st; s4[w] = st2;
    }
    __syncthreads();
    if (tid == 0) {
        double A = s1[0] + s1[1] + s1[2] + s1[3];
        double B = s2[0] + s2[1] + s2[2] + s2[3];
        rowsum[x] = A;
        p1[2 * x]     = s3[0] + s3[1] + s3[2] + s3[3];
        p1[2 * x + 1] = s4[0] + s4[1] + s4[2] + s4[3];
        s1[0] = A; s2[0] = B;
    }
    __syncthreads();
    if (tid < NA) {
        double h1 = 0, h2 = 0;
        for (int y = 0; y < tid; y++)          { float v = row[y]; h1 += v; h2 += (double)v * v; }
        for (int y = tid + KWIN; y < 2048; y++){ float v = row[y]; h1 += v; h2 += (double)v * v; }
        Rv [(size_t)tid * 2048 + x] = s1[0] - h1;
        Rv2[(size_t)tid * 2048 + x] = s2[0] - h2;
    }
}

// ---------------- K2: global scalars ----------------
__global__ void k_scal(const double* __restrict__ p1, const double* __restrict__ rowsum,
                       float* __restrict__ scal) {
    __shared__ double rs[512 * 3];
    int tid = threadIdx.x;
    double st = 0, st2 = 0, sf = 0;
    for (int k = 0; k < 4; k++) {
        int x = tid + 512 * k;
        st += p1[2 * x]; st2 += p1[2 * x + 1]; sf += rowsum[x];
    }
    rs[tid] = st; rs[512 + tid] = st2; rs[1024 + tid] = sf;
    __syncthreads();
    for (int off = 256; off > 0; off >>= 1) {
        if (tid < off) {
            rs[tid] += rs[tid + off];
            rs[512 + tid] += rs[512 + tid + off];
            rs[1024 + tid] += rs[1024 + tid + off];
        }
        __syncthreads();
    }
    if (tid == 0) {
        double N = (double)HC * (double)HC;
        double s = rs[0], s2 = rs[512], sfd = rs[1024];
        float mt = (float)(s / N);
        float mf = (float)(sfd / N);
        double m = (double)mt;
        double tv = s2 - 2.0 * m * s + N * m * m;
        scal[0] = mt;
        scal[1] = mf;
        scal[2] = (float)tv + 1e-8f;
    }
}

// ---------------- K3: column totals + head/tail -> den[441] (21 blocks) -------------
__global__ void k_dencol(const double* __restrict__ Rv, const double* __restrict__ Rv2,
                         const float* __restrict__ scal, float* __restrict__ den) {
    __shared__ double sm0[4], sm1[4];
    int j = blockIdx.x, tid = threadIdx.x;
    const double* R0 = Rv  + (size_t)j * 2048;
    const double* R1 = Rv2 + (size_t)j * 2048;
    double s0 = 0, s1 = 0;
    for (int x = tid; x < 2048; x += 256) { s0 += R0[x]; s1 += R1[x]; }
    for (int o = 32; o > 0; o >>= 1) { s0 += __shfl_down(s0, o); s1 += __shfl_down(s1, o); }
    if ((tid & 63) == 0) { sm0[tid >> 6] = s0; sm1[tid >> 6] = s1; }
    __syncthreads();
    if (tid < NA) {
        double T0 = sm0[0] + sm0[1] + sm0[2] + sm0[3];
        double T1 = sm1[0] + sm1[1] + sm1[2] + sm1[3];
        int i = tid;
        double h0 = 0, h1 = 0;
        for (int x = 0; x < i; x++)           { h0 += R0[x]; h1 += R1[x]; }
        for (int x = i + KWIN; x < 2048; x++) { h0 += R0[x]; h1 += R1[x]; }
        double area = (double)KWIN * (double)KWIN;
        float lm0 = (float)((T0 - h0) / area);
        float lm1 = (float)((T1 - h1) / area);
        float iv = lm1 - (lm0 * lm0) / 4194304.0f + 1e-8f;
        if (iv < 0.f) iv = 0.f;
        den[i * NA + j] = sqrtf(scal[2] * iv);
    }
}

// ---------------- K4: MFMA circular cross-correlation ----------------
// cc[a,b] = sum_t sum_y I[t+a-10, y] * T[t, y-b+10]  (circular, means pre-subtracted)
// 64 t-rows per block (2 sub-tiles), I staged once (95 rows), T re-staged per sub-tile.
__global__ __launch_bounds__(256) void k_corr(const float* __restrict__ fr,
                                              const float* __restrict__ tp,
                                              const float* __restrict__ scal,
                                              float* __restrict__ cp) {
    __shared__ __align__(16) char smem[ILDS_BYTES + TLDS_BYTES];
    unsigned short* Il = (unsigned short*)smem;
    unsigned short* Tl = (unsigned short*)(smem + ILDS_BYTES);
    unsigned* Iw = (unsigned*)smem;
    unsigned* Tw = (unsigned*)Tl;
    int tid = threadIdx.x;
    int bid = blockIdx.x;
    int t0 = (bid >> 4) * TCH;
    int y0 = (bid & 15) * YCB;
    float mt = scal[0], mf = scal[1];

    // stage I: rows t0-10 .. t0+84 (mod 2048), cols [y0, y0+128)
    for (int idx = tid; idx < ILDS_ROWS * 32; idx += 256) {
        int row = idx >> 5, pc4 = idx & 31;
        int grow = (t0 - 10 + row) & (HC - 1);
        float4 v = *(const float4*)&fr[(size_t)(OFF + grow) * H0 + OFF + y0 + 4 * pc4];
        uint2 pk;
        pk.x = f2bf_pack(v.x - mf, v.y - mf);
        pk.y = f2bf_pack(v.z - mf, v.w - mf);
        *(uint2*)(Iw + row * (ILDS_STR / 2) + 2 * pc4) = pk;
    }

    int l = tid & 63, wv = tid >> 6;
    int kg = l >> 4, i16 = l & 15;
    f32x4 acc00 = {0.f, 0.f, 0.f, 0.f};
    f32x4 acc01 = {0.f, 0.f, 0.f, 0.f};
    f32x4 acc10 = {0.f, 0.f, 0.f, 0.f};
    f32x4 acc11 = {0.f, 0.f, 0.f, 0.f};

    for (int s = 0; s < 2; ++s) {
        // stage T sub-tile: rows t0+32s+row, region j in [0,176), 4 parity copies
        for (int u = tid; u < 32 * 11; u += 256) {
            int row = u / 11, k = u - row * 11;
            int e0 = 16 * k;
            const float* srcT = tp + (size_t)(OFF + t0 + 32 * s + row) * H0 + OFF;
            unsigned w[10];
#pragma unroll
            for (int q4 = 0; q4 < 5; ++q4) {
                int gcol = (y0 - 24 + e0 + 4 * q4) & (HC - 1);
                float4 v = *(const float4*)&srcT[gcol];
                w[2 * q4]     = f2bf_pack(v.x - mt, v.y - mt);
                w[2 * q4 + 1] = f2bf_pack(v.z - mt, v.w - mt);
            }
            unsigned* dst = Tw + row * T_ROWW + 8 * k;
            uint4 c0a = {w[0], w[1], w[2], w[3]};
            uint4 c0b = {w[4], w[5], w[6], w[7]};
            *(uint4*)(dst) = c0a;
            *(uint4*)(dst + 4) = c0b;
            unsigned d1[8], d2[8], d3[8];
#pragma unroll
            for (int jj = 0; jj < 8; ++jj) {
                d1[jj] = (w[jj] >> 16) | (w[jj + 1] << 16);
                d2[jj] = w[jj + 1];
                d3[jj] = (w[jj + 1] >> 16) | (w[jj + 2] << 16);
            }
            uint4 c1a = {d1[0], d1[1], d1[2], d1[3]}, c1b = {d1[4], d1[5], d1[6], d1[7]};
            uint4 c2a = {d2[0], d2[1], d2[2], d2[3]}, c2b = {d2[4], d2[5], d2[6], d2[7]};
            uint4 c3a = {d3[0], d3[1], d3[2], d3[3]}, c3b = {d3[4], d3[5], d3[6], d3[7]};
            *(uint4*)(dst + CSTR_DW) = c1a;     *(uint4*)(dst + CSTR_DW + 4) = c1b;
            *(uint4*)(dst + 2 * CSTR_DW) = c2a; *(uint4*)(dst + 2 * CSTR_DW + 4) = c2b;
            *(uint4*)(dst + 3 * CSTR_DW) = c3a; *(uint4*)(dst + 3 * CSTR_DW + 4) = c3b;
        }
        __syncthreads();

        for (int dt = 0; dt < 8; ++dt) {
            int tl = 8 * wv + dt;
            const unsigned short* Trow = Tl + tl * T_ROWE;
            const unsigned short* Ir0 = Il + (32 * s + tl + i16) * ILDS_STR;
            const unsigned short* Ir1 = Ir0 + 16 * ILDS_STR;
#pragma unroll
            for (int ks = 0; ks < 4; ++ks) {
                int yk = 32 * ks + 8 * kg;
                short8 a0 = *(const short8*)(Ir0 + yk);
                short8 a1 = *(const short8*)(Ir1 + yk);
                union { uint2 u[2]; short8 s; } ub0, ub1;
                {
                    int s0 = yk - i16 + 34;                 // nt=0 (b = i16)
                    int c = s0 & 3;
                    const unsigned short* q = Trow + c * CSTR_E + (s0 - c);
                    ub0.u[0] = *(const uint2*)q;
                    ub0.u[1] = *(const uint2*)(q + 4);
                }
                {
                    int s0 = yk - i16 + 18;                 // nt=1 (b = 16+i16)
                    int c = s0 & 3;
                    const unsigned short* q = Trow + c * CSTR_E + (s0 - c);
                    ub1.u[0] = *(const uint2*)q;
                    ub1.u[1] = *(const uint2*)(q + 4);
                }
                acc00 = __builtin_amdgcn_mfma_f32_16x16x32_bf16(a0, ub0.s, acc00, 0, 0, 0);
                acc01 = __builtin_amdgcn_mfma_f32_16x16x32_bf16(a0, ub1.s, acc01, 0, 0, 0);
                acc10 = __builtin_amdgcn_mfma_f32_16x16x32_bf16(a1, ub0.s, acc10, 0, 0, 0);
                acc11 = __builtin_amdgcn_mfma_f32_16x16x32_bf16(a1, ub1.s, acc11, 0, 0, 0);
            }
        }
        __syncthreads();        // waves done with T buffer before next sub-tile restage
    }

    float* buf = (float*)smem;          // 4 waves x 32x32 f32 = 16 KB (fits I region)
    {
        int r0w = 4 * kg;
#pragma unroll
        for (int r = 0; r < 4; ++r) {
            buf[wv * 1024 + (r0w + r) * 32 + i16]           = acc00[r];
            buf[wv * 1024 + (r0w + r) * 32 + 16 + i16]      = acc01[r];
            buf[wv * 1024 + (16 + r0w + r) * 32 + i16]      = acc10[r];
            buf[wv * 1024 + (16 + r0w + r) * 32 + 16 + i16] = acc11[r];
        }
    }
    __syncthreads();
    for (int e = tid; e < 1024; e += 256) {
        int a = e >> 5, b = e & 31;
        if (a < NA && b < NA)
            cp[(size_t)bid * NAB + a * NA + b] =
                buf[e] + buf[1024 + e] + buf[2048 + e] + buf[3072 + e];
    }
}

// ---------------- K5a: deterministic reduction of per-block partials ----------------
__global__ void k_ccreduce(const float* __restrict__ cp, double* __restrict__ ccv) {
    __shared__ double red[256];
    int ab = blockIdx.x, tid = threadIdx.x;
    double s = 0;
    for (int blk = tid; blk < NBLK; blk += 256) s += (double)cp[(size_t)blk * NAB + ab];
    red[tid] = s;
    __syncthreads();
    for (int off = 128; off > 0; off >>= 1) {
        if (tid < off) red[tid] += red[tid + off];
        __syncthreads();
    }
    if (tid == 0) ccv[ab] = red[0];
}

// ---------------- K5b: ncc, argmax (first-max), log-parabola ----------------
__global__ void k_peak(const double* __restrict__ ccv, const float* __restrict__ den,
                       float* __restrict__ scal, float* __restrict__ out) {
    __shared__ float ncc[NAB];
    __shared__ float bv[512];
    __shared__ int bi_[512];
    int tid = threadIdx.x;
    if (tid < NAB) {
        float c = fabsf((float)ccv[tid]);
        float v = c / den[tid];
        if (v != v) v = 0.f;
        ncc[tid] = v;
    }
    __syncthreads();
    bv[tid] = (tid < NAB) ? ncc[tid] : -1e38f;
    bi_[tid] = (tid < NAB) ? tid : 0;
    __syncthreads();
    for (int off = 256; off > 0; off >>= 1) {
        if (tid < off) {
            float v2 = bv[tid + off]; int i2 = bi_[tid + off];
            if (v2 > bv[tid] || (v2 == bv[tid] && i2 < bi_[tid])) { bv[tid] = v2; bi_[tid] = i2; }
        }
        __syncthreads();
    }
    if (tid == 0) {
        int am = bi_[0];
        int sx = am / NA, sy = am - (am / NA) * NA;
        auto L = [&](int i, int j) {
            int ii = ((i % NA) + NA) % NA;
            int jj = ((j % NA) + NA) % NA;
            return logf(ncc[ii * NA + jj]);
        };
        float l0 = L(sx, sy);
        float lxm = L(sx - 1, sy), lxp = L(sx + 1, sy);
        float lym = L(sx, sy - 1), lyp = L(sx, sy + 1);
        float four = 4.f * l0;
        float shx = -(float)(sx - 10) - (lxm - lxp) / (2.f * lxm - four + 2.f * lxp);
        float shy = -(float)(sy - 10) - (lym - lyp) / (2.f * lym - four + 2.f * lyp);
        scal[3] = shx; scal[4] = shy;
        out[(size_t)H0 * H0]     = shx;
        out[(size_t)H0 * H0 + 1] = shy;
    }
}

// ---------------- K6: bilinear translate + transposed flatten ----------------
__global__ __launch_bounds__(256) void k_translate(const float* __restrict__ fr,
                                                   const float* __restrict__ scal,
                                                   float* __restrict__ out) {
    __shared__ float T[65 * 67];
    int tid = threadIdx.x;
    int bx = blockIdx.x % 48, by = blockIdx.x / 48;
    int r0 = bx * 64, c0 = by * 64;
    float dx = scal[3], dy = scal[4];
    float fy = -dy, Fy = floorf(fy), wr = fy - Fy;
    float fx = -dx, Fx = floorf(fx), wc = fx - Fx;
    int R0 = r0 + (int)Fy, C0 = c0 + (int)Fx;
    for (int idx = tid; idx < 65 * 65; idx += 256) {
        int i = idx / 65, j = idx - i * 65;
        int gr = R0 + i, gc = C0 + j;
        float v = 0.f;
        if (gr >= 0 && gr < H0 && gc >= 0 && gc < H0) v = fr[(size_t)gr * H0 + gc];
        T[i * 67 + j] = v;
    }
    __syncthreads();
    float w00 = (1.f - wr) * (1.f - wc), w01 = (1.f - wr) * wc;
    float w10 = wr * (1.f - wc),        w11 = wr * wc;
    int rl = (tid & 15) * 4;
    int cl0 = tid >> 4;
    auto S = [&](int rr, int cl) {
        return w00 * T[rr * 67 + cl] + w01 * T[rr * 67 + cl + 1] +
               w10 * T[(rr + 1) * 67 + cl] + w11 * T[(rr + 1) * 67 + cl + 1];
    };
    for (int q = 0; q < 4; q++) {
        int cl = cl0 + q * 16;
        float4 res = make_float4(S(rl, cl), S(rl + 1, cl), S(rl + 2, cl), S(rl + 3, cl));
        *reinterpret_cast<float4*>(&out[(size_t)(c0 + cl) * H0 + r0 + rl]) = res;
    }
}

extern "C" void kernel_launch(void* const* d_in, const int* in_sizes, int n_in,
                              void* d_out, int out_size, void* d_ws, size_t ws_size,
                              hipStream_t stream) {
    const float* fr = (const float*)d_in[0];
    const float* tp = (const float*)d_in[1];
    float* out = (float*)d_out;
    char* ws = (char*)d_ws;
    float*  scal = (float*)(ws + WS_SCAL);
    double* p1   = (double*)(ws + WS_P1);
    double* rsum = (double*)(ws + WS_RS);
    double* Rv   = (double*)(ws + WS_R);
    double* Rv2  = (double*)(ws + WS_R2);
    float*  den  = (float*)(ws + WS_DEN);
    double* ccv  = (double*)(ws + WS_CCV);
    float*  cp   = (float*)(ws + WS_CP);

    k_rowpool   <<<2048, 256, 0, stream>>>(fr, tp, Rv, Rv2, rsum, p1);
    k_scal      <<<1, 512, 0, stream>>>(p1, rsum, scal);
    k_dencol    <<<NA, 256, 0, stream>>>(Rv, Rv2, scal, den);
    k_corr      <<<NBLK, 256, 0, stream>>>(fr, tp, scal, cp);
    k_ccreduce  <<<NAB, 256, 0, stream>>>(cp, ccv);
    k_peak      <<<1, 512, 0, stream>>>(ccv, den, scal, out);
    k_translate <<<2304, 256, 0, stream>>>(fr, scal, out);
}

// Round 7
// 68.656 us; speedup vs baseline: 3.1237x; 1.0365x over previous
//
#include <hip/hip_runtime.h>
#include <math.h>

#define H0 3072
#define HC 2048
#define OFF 512
#define NA 21
#define NAB 441
#define KWIN 2028

// ---- k_corr (MFMA) tiling ----
#define TCH 64                   // t-rows per block (2 sub-tiles of 32)
#define YCB 128                  // y per block
#define NTB 32                   // 2048/TCH
#define NYB 16                   // 2048/YCB
#define NBLK (NTB * NYB)         // 512
#define ILDS_STR 136             // elems
#define ILDS_ROWS 95             // TCH + 31
#define ILDS_BYTES (ILDS_ROWS * ILDS_STR * 2)   // 25840
// T: 4 parity-shifted copies, per-copy 32 rows x 176 elems, +8dw stagger per copy
#define T_ROWE 176               // elems per row
#define T_ROWW 88                // dwords per row
#define CSTR_DW 2824             // 32*88 + 8 (stagger: 2824%32 == 8)
#define CSTR_E  5648
#define TLDS_BYTES (4 * CSTR_DW * 4)            // 45184
// total smem = 71024 B -> 2 blocks/CU

// ws layout (bytes)
#define WS_SCAL 128              // floats: [3]sh_x [4]sh_y (written by k_peak)
#define WS_CC0  192              // 1 double: constant correction C
#define WS_P1   4096             // 2048*2 doubles (per-row tp sums)
#define WS_RS   36864            // 2048 doubles (fr row sums)
#define WS_R    65536            // Rv : [j][x] 21*2048 doubles
#define WS_R2   409600           // Rv2
#define WS_DEN  753664           // 441 floats
#define WS_CCV  757760           // 441 doubles
#define WS_CP   786432           // NBLK*441 floats

typedef __attribute__((ext_vector_type(8))) short short8;
typedef __attribute__((ext_vector_type(4))) float f32x4;

static __device__ __forceinline__ unsigned f2bf_pack(float a, float b) {
    union { float f; unsigned u; } x, y; x.f = a; y.f = b;
    unsigned ra = (x.u + 0x7fff + ((x.u >> 16) & 1)) >> 16;
    unsigned rb = (y.u + 0x7fff + ((y.u >> 16) & 1)) >> 16;
    return ra | (rb << 16);
}

// ---------------- K1: fr row sums + window sums + tp row sums (fused) ----------------
__global__ __launch_bounds__(256) void k_rowpool(const float* __restrict__ fr,
                          const float* __restrict__ tp,
                          double* __restrict__ Rv, double* __restrict__ Rv2,
                          double* __restrict__ rowsum, double* __restrict__ p1) {
    __shared__ float row[2048];
    __shared__ double s1[4], s2[4], s3[4], s4[4];
    int x = blockIdx.x, tid = threadIdx.x;
    const float* srcF = fr + (size_t)(OFF + x) * H0 + OFF;
    const float* srcT = tp + (size_t)(OFF + x) * H0 + OFF;
    float4 v0 = *(const float4*)&srcF[4 * tid];
    float4 v1 = *(const float4*)&srcF[4 * tid + 1024];
    *(float4*)&row[4 * tid] = v0;
    *(float4*)&row[4 * tid + 1024] = v1;
    double a = ((double)v0.x + v0.y) + ((double)v0.z + v0.w) +
               ((double)v1.x + v1.y) + ((double)v1.z + v1.w);
    double b = ((double)v0.x * v0.x + (double)v0.y * v0.y) +
               ((double)v0.z * v0.z + (double)v0.w * v0.w) +
               ((double)v1.x * v1.x + (double)v1.y * v1.y) +
               ((double)v1.z * v1.z + (double)v1.w * v1.w);
    float4 t0 = *(const float4*)&srcT[4 * tid];
    float4 t1 = *(const float4*)&srcT[4 * tid + 1024];
    double st = ((double)t0.x + t0.y) + ((double)t0.z + t0.w) +
                ((double)t1.x + t1.y) + ((double)t1.z + t1.w);
    double st2 = ((double)t0.x * t0.x + (double)t0.y * t0.y) +
                 ((double)t0.z * t0.z + (double)t0.w * t0.w) +
                 ((double)t1.x * t1.x + (double)t1.y * t1.y) +
                 ((double)t1.z * t1.z + (double)t1.w * t1.w);
    for (int o = 32; o > 0; o >>= 1) {
        a += __shfl_down(a, o); b += __shfl_down(b, o);
        st += __shfl_down(st, o); st2 += __shfl_down(st2, o);
    }
    if ((tid & 63) == 0) {
        int w = tid >> 6;
        s1[w] = a; s2[w] = b; s3[w] = st; s4[w] = st2;
    }
    __syncthreads();
    if (tid == 0) {
        double A = s1[0] + s1[1] + s1[2] + s1[3];
        double B = s2[0] + s2[1] + s2[2] + s2[3];
        rowsum[x] = A;
        p1[2 * x]     = s3[0] + s3[1] + s3[2] + s3[3];
        p1[2 * x + 1] = s4[0] + s4[1] + s4[2] + s4[3];
        s1[0] = A; s2[0] = B;
    }
    __syncthreads();
    if (tid < NA) {
        double h1 = 0, h2 = 0;
        for (int y = 0; y < tid; y++)          { float v = row[y]; h1 += v; h2 += (double)v * v; }
        for (int y = tid + KWIN; y < 2048; y++){ float v = row[y]; h1 += v; h2 += (double)v * v; }
        Rv [(size_t)tid * 2048 + x] = s1[0] - h1;
        Rv2[(size_t)tid * 2048 + x] = s2[0] - h2;
    }
}

// -------- K2: den[441] + correction constant C (21 blocks; scalars recomputed locally) ----
__global__ __launch_bounds__(256) void k_dencol(const double* __restrict__ Rv,
                         const double* __restrict__ Rv2,
                         const double* __restrict__ p1, const double* __restrict__ rowsum,
                         float* __restrict__ den, double* __restrict__ Cc) {
    __shared__ double sm0[4], sm1[4], smt[4], smt2[4], smf[4];
    int j = blockIdx.x, tid = threadIdx.x;
    const double* R0 = Rv  + (size_t)j * 2048;
    const double* R1 = Rv2 + (size_t)j * 2048;
    double s0 = 0, s1 = 0, st = 0, st2 = 0, sf = 0;
    for (int x = tid; x < 2048; x += 256) {
        s0 += R0[x]; s1 += R1[x];
        st += p1[2 * x]; st2 += p1[2 * x + 1]; sf += rowsum[x];
    }
    for (int o = 32; o > 0; o >>= 1) {
        s0 += __shfl_down(s0, o); s1 += __shfl_down(s1, o);
        st += __shfl_down(st, o); st2 += __shfl_down(st2, o); sf += __shfl_down(sf, o);
    }
    if ((tid & 63) == 0) {
        int w = tid >> 6;
        sm0[w] = s0; sm1[w] = s1; smt[w] = st; smt2[w] = st2; smf[w] = sf;
    }
    __syncthreads();
    if (tid < NA) {
        double T0 = sm0[0] + sm0[1] + sm0[2] + sm0[3];
        double T1 = sm1[0] + sm1[1] + sm1[2] + sm1[3];
        double ST = smt[0] + smt[1] + smt[2] + smt[3];
        double ST2 = smt2[0] + smt2[1] + smt2[2] + smt2[3];
        double SF = smf[0] + smf[1] + smf[2] + smf[3];
        double N = (double)HC * (double)HC;
        float mt = (float)(ST / N);
        double m = (double)mt;
        float tvar = (float)(ST2 - 2.0 * m * ST + N * m * m) + 1e-8f;
        int i = tid;
        double h0 = 0, h1 = 0;
        for (int x = 0; x < i; x++)           { h0 += R0[x]; h1 += R1[x]; }
        for (int x = i + KWIN; x < 2048; x++) { h0 += R0[x]; h1 += R1[x]; }
        double area = (double)KWIN * (double)KWIN;
        float lm0 = (float)((T0 - h0) / area);
        float lm1 = (float)((T1 - h1) / area);
        float iv = lm1 - (lm0 * lm0) / 4194304.0f + 1e-8f;
        if (iv < 0.f) iv = 0.f;
        den[i * NA + j] = sqrtf(tvar * iv);
        if (j == 0 && i == 0) {
            float mf = (float)(SF / N);
            // C = mf*S_T + mt*S_I - N*mf*mt  (lag-independent zero-mean correction)
            *Cc = (double)mf * ST + (double)mt * SF - N * (double)mf * (double)mt;
        }
    }
}

// ---------------- K3: MFMA circular cross-correlation on RAW values ----------------
// cc_raw[a,b] = sum_t sum_y I[t+a-10, y] * T[t, y-b+10]  (circular)
// zero-mean correction applied later as the constant C (full-period circularity).
__global__ __launch_bounds__(256) void k_corr(const float* __restrict__ fr,
                                              const float* __restrict__ tp,
                                              float* __restrict__ cp) {
    __shared__ __align__(16) char smem[ILDS_BYTES + TLDS_BYTES];
    unsigned short* Il = (unsigned short*)smem;
    unsigned short* Tl = (unsigned short*)(smem + ILDS_BYTES);
    unsigned* Iw = (unsigned*)smem;
    unsigned* Tw = (unsigned*)Tl;
    int tid = threadIdx.x;
    int bid = blockIdx.x;
    int t0 = (bid >> 4) * TCH;
    int y0 = (bid & 15) * YCB;

    // stage I: rows t0-10 .. t0+84 (mod 2048), cols [y0, y0+128)
    for (int idx = tid; idx < ILDS_ROWS * 32; idx += 256) {
        int row = idx >> 5, pc4 = idx & 31;
        int grow = (t0 - 10 + row) & (HC - 1);
        float4 v = *(const float4*)&fr[(size_t)(OFF + grow) * H0 + OFF + y0 + 4 * pc4];
        uint2 pk;
        pk.x = f2bf_pack(v.x, v.y);
        pk.y = f2bf_pack(v.z, v.w);
        *(uint2*)(Iw + row * (ILDS_STR / 2) + 2 * pc4) = pk;
    }

    int l = tid & 63, wv = tid >> 6;
    int kg = l >> 4, i16 = l & 15;
    f32x4 acc00 = {0.f, 0.f, 0.f, 0.f};
    f32x4 acc01 = {0.f, 0.f, 0.f, 0.f};
    f32x4 acc10 = {0.f, 0.f, 0.f, 0.f};
    f32x4 acc11 = {0.f, 0.f, 0.f, 0.f};

    for (int s = 0; s < 2; ++s) {
        // stage T sub-tile: rows t0+32s+row, region j in [0,176), 4 parity copies
        for (int u = tid; u < 32 * 11; u += 256) {
            int row = u / 11, k = u - row * 11;
            int e0 = 16 * k;
            const float* srcT = tp + (size_t)(OFF + t0 + 32 * s + row) * H0 + OFF;
            unsigned w[10];
#pragma unroll
            for (int q4 = 0; q4 < 5; ++q4) {
                int gcol = (y0 - 24 + e0 + 4 * q4) & (HC - 1);
                float4 v = *(const float4*)&srcT[gcol];
                w[2 * q4]     = f2bf_pack(v.x, v.y);
                w[2 * q4 + 1] = f2bf_pack(v.z, v.w);
            }
            unsigned* dst = Tw + row * T_ROWW + 8 * k;
            uint4 c0a = {w[0], w[1], w[2], w[3]};
            uint4 c0b = {w[4], w[5], w[6], w[7]};
            *(uint4*)(dst) = c0a;
            *(uint4*)(dst + 4) = c0b;
            unsigned d1[8], d2[8], d3[8];
#pragma unroll
            for (int jj = 0; jj < 8; ++jj) {
                d1[jj] = (w[jj] >> 16) | (w[jj + 1] << 16);
                d2[jj] = w[jj + 1];
                d3[jj] = (w[jj + 1] >> 16) | (w[jj + 2] << 16);
            }
            uint4 c1a = {d1[0], d1[1], d1[2], d1[3]}, c1b = {d1[4], d1[5], d1[6], d1[7]};
            uint4 c2a = {d2[0], d2[1], d2[2], d2[3]}, c2b = {d2[4], d2[5], d2[6], d2[7]};
            uint4 c3a = {d3[0], d3[1], d3[2], d3[3]}, c3b = {d3[4], d3[5], d3[6], d3[7]};
            *(uint4*)(dst + CSTR_DW) = c1a;     *(uint4*)(dst + CSTR_DW + 4) = c1b;
            *(uint4*)(dst + 2 * CSTR_DW) = c2a; *(uint4*)(dst + 2 * CSTR_DW + 4) = c2b;
            *(uint4*)(dst + 3 * CSTR_DW) = c3a; *(uint4*)(dst + 3 * CSTR_DW + 4) = c3b;
        }
        __syncthreads();

        for (int dt = 0; dt < 8; ++dt) {
            int tl = 8 * wv + dt;
            const unsigned short* Trow = Tl + tl * T_ROWE;
            const unsigned short* Ir0 = Il + (32 * s + tl + i16) * ILDS_STR;
            const unsigned short* Ir1 = Ir0 + 16 * ILDS_STR;
#pragma unroll
            for (int ks = 0; ks < 4; ++ks) {
                int yk = 32 * ks + 8 * kg;
                short8 a0 = *(const short8*)(Ir0 + yk);
                short8 a1 = *(const short8*)(Ir1 + yk);
                union { uint2 u[2]; short8 s; } ub0, ub1;
                {
                    int s0 = yk - i16 + 34;                 // nt=0 (b = i16)
                    int c = s0 & 3;
                    const unsigned short* q = Trow + c * CSTR_E + (s0 - c);
                    ub0.u[0] = *(const uint2*)q;
                    ub0.u[1] = *(const uint2*)(q + 4);
                }
                {
                    int s0 = yk - i16 + 18;                 // nt=1 (b = 16+i16)
                    int c = s0 & 3;
                    const unsigned short* q = Trow + c * CSTR_E + (s0 - c);
                    ub1.u[0] = *(const uint2*)q;
                    ub1.u[1] = *(const uint2*)(q + 4);
                }
                acc00 = __builtin_amdgcn_mfma_f32_16x16x32_bf16(a0, ub0.s, acc00, 0, 0, 0);
                acc01 = __builtin_amdgcn_mfma_f32_16x16x32_bf16(a0, ub1.s, acc01, 0, 0, 0);
                acc10 = __builtin_amdgcn_mfma_f32_16x16x32_bf16(a1, ub0.s, acc10, 0, 0, 0);
                acc11 = __builtin_amdgcn_mfma_f32_16x16x32_bf16(a1, ub1.s, acc11, 0, 0, 0);
            }
        }
        __syncthreads();        // waves done with T buffer before next sub-tile restage
    }

    float* buf = (float*)smem;          // 4 waves x 32x32 f32 = 16 KB (fits I region)
    {
        int r0w = 4 * kg;
#pragma unroll
        for (int r = 0; r < 4; ++r) {
            buf[wv * 1024 + (r0w + r) * 32 + i16]           = acc00[r];
            buf[wv * 1024 + (r0w + r) * 32 + 16 + i16]      = acc01[r];
            buf[wv * 1024 + (16 + r0w + r) * 32 + i16]      = acc10[r];
            buf[wv * 1024 + (16 + r0w + r) * 32 + 16 + i16] = acc11[r];
        }
    }
    __syncthreads();
    for (int e = tid; e < 1024; e += 256) {
        int a = e >> 5, b = e & 31;
        if (a < NA && b < NA)
            cp[(size_t)bid * NAB + a * NA + b] =
                buf[e] + buf[1024 + e] + buf[2048 + e] + buf[3072 + e];
    }
}

// ---------------- K4: deterministic reduction of per-block partials ----------------
__global__ void k_ccreduce(const float* __restrict__ cp, double* __restrict__ ccv) {
    __shared__ double red[256];
    int ab = blockIdx.x, tid = threadIdx.x;
    double s = 0;
    for (int blk = tid; blk < NBLK; blk += 256) s += (double)cp[(size_t)blk * NAB + ab];
    red[tid] = s;
    __syncthreads();
    for (int off = 128; off > 0; off >>= 1) {
        if (tid < off) red[tid] += red[tid + off];
        __syncthreads();
    }
    if (tid == 0) ccv[ab] = red[0];
}

// ---------------- K5: ncc (with constant correction), argmax, log-parabola ----------
__global__ void k_peak(const double* __restrict__ ccv, const float* __restrict__ den,
                       const double* __restrict__ Cc,
                       float* __restrict__ scal, float* __restrict__ out) {
    __shared__ float ncc[NAB];
    __shared__ float bv[512];
    __shared__ int bi_[512];
    int tid = threadIdx.x;
    double C = *Cc;
    if (tid < NAB) {
        float c = fabsf((float)(ccv[tid] - C));
        float v = c / den[tid];
        if (v != v) v = 0.f;
        ncc[tid] = v;
    }
    __syncthreads();
    bv[tid] = (tid < NAB) ? ncc[tid] : -1e38f;
    bi_[tid] = (tid < NAB) ? tid : 0;
    __syncthreads();
    for (int off = 256; off > 0; off >>= 1) {
        if (tid < off) {
            float v2 = bv[tid + off]; int i2 = bi_[tid + off];
            if (v2 > bv[tid] || (v2 == bv[tid] && i2 < bi_[tid])) { bv[tid] = v2; bi_[tid] = i2; }
        }
        __syncthreads();
    }
    if (tid == 0) {
        int am = bi_[0];
        int sx = am / NA, sy = am - (am / NA) * NA;
        auto L = [&](int i, int j) {
            int ii = ((i % NA) + NA) % NA;
            int jj = ((j % NA) + NA) % NA;
            return logf(ncc[ii * NA + jj]);
        };
        float l0 = L(sx, sy);
        float lxm = L(sx - 1, sy), lxp = L(sx + 1, sy);
        float lym = L(sx, sy - 1), lyp = L(sx, sy + 1);
        float four = 4.f * l0;
        float shx = -(float)(sx - 10) - (lxm - lxp) / (2.f * lxm - four + 2.f * lxp);
        float shy = -(float)(sy - 10) - (lym - lyp) / (2.f * lym - four + 2.f * lyp);
        scal[3] = shx; scal[4] = shy;
        out[(size_t)H0 * H0]     = shx;
        out[(size_t)H0 * H0 + 1] = shy;
    }
}

// ---------------- K6: bilinear translate + transposed flatten ----------------
__global__ __launch_bounds__(256) void k_translate(const float* __restrict__ fr,
                                                   const float* __restrict__ scal,
                                                   float* __restrict__ out) {
    __shared__ float T[65 * 67];
    int tid = threadIdx.x;
    int bx = blockIdx.x % 48, by = blockIdx.x / 48;
    int r0 = bx * 64, c0 = by * 64;
    float dx = scal[3], dy = scal[4];
    float fy = -dy, Fy = floorf(fy), wr = fy - Fy;
    float fx = -dx, Fx = floorf(fx), wc = fx - Fx;
    int R0 = r0 + (int)Fy, C0 = c0 + (int)Fx;
    for (int idx = tid; idx < 65 * 65; idx += 256) {
        int i = idx / 65, j = idx - i * 65;
        int gr = R0 + i, gc = C0 + j;
        float v = 0.f;
        if (gr >= 0 && gr < H0 && gc >= 0 && gc < H0) v = fr[(size_t)gr * H0 + gc];
        T[i * 67 + j] = v;
    }
    __syncthreads();
    float w00 = (1.f - wr) * (1.f - wc), w01 = (1.f - wr) * wc;
    float w10 = wr * (1.f - wc),        w11 = wr * wc;
    int rl = (tid & 15) * 4;
    int cl0 = tid >> 4;
    auto S = [&](int rr, int cl) {
        return w00 * T[rr * 67 + cl] + w01 * T[rr * 67 + cl + 1] +
               w10 * T[(rr + 1) * 67 + cl] + w11 * T[(rr + 1) * 67 + cl + 1];
    };
    for (int q = 0; q < 4; q++) {
        int cl = cl0 + q * 16;
        float4 res = make_float4(S(rl, cl), S(rl + 1, cl), S(rl + 2, cl), S(rl + 3, cl));
        *reinterpret_cast<float4*>(&out[(size_t)(c0 + cl) * H0 + r0 + rl]) = res;
    }
}

extern "C" void kernel_launch(void* const* d_in, const int* in_sizes, int n_in,
                              void* d_out, int out_size, void* d_ws, size_t ws_size,
                              hipStream_t stream) {
    const float* fr = (const float*)d_in[0];
    const float* tp = (const float*)d_in[1];
    float* out = (float*)d_out;
    char* ws = (char*)d_ws;
    float*  scal = (float*)(ws + WS_SCAL);
    double* Cc   = (double*)(ws + WS_CC0);
    double* p1   = (double*)(ws + WS_P1);
    double* rsum = (double*)(ws + WS_RS);
    double* Rv   = (double*)(ws + WS_R);
    double* Rv2  = (double*)(ws + WS_R2);
    float*  den  = (float*)(ws + WS_DEN);
    double* ccv  = (double*)(ws + WS_CCV);
    float*  cp   = (float*)(ws + WS_CP);

    k_rowpool   <<<2048, 256, 0, stream>>>(fr, tp, Rv, Rv2, rsum, p1);
    k_dencol    <<<NA, 256, 0, stream>>>(Rv, Rv2, p1, rsum, den, Cc);
    k_corr      <<<NBLK, 256, 0, stream>>>(fr, tp, cp);
    k_ccreduce  <<<NAB, 256, 0, stream>>>(cp, ccv);
    k_peak      <<<1, 512, 0, stream>>>(ccv, den, Cc, scal, out);
    k_translate <<<2304, 256, 0, stream>>>(fr, scal, out);
}